// Round 1
// baseline (4237.972 us; speedup 1.0000x reference)
//
#include <hip/hip_runtime.h>
#include <math.h>

static constexpr int NPTS = 1024;
static constexpr int NB = 64;
static constexpr int NPOINTS = NB * NPTS;   // 65536
static constexpr int KNB = 16;

// ---------------- squared norms (order must match knn dot chain) ----------------
template<int C>
__global__ __launch_bounds__(64) void sqnorm_kernel(const float* __restrict__ x,
                                                    float* __restrict__ sq) {
    int p = blockIdx.x * 64 + threadIdx.x;
    const float* xp = x + (size_t)p * C;
    float s;
    if constexpr (C == 1) {
        s = xp[0] * xp[0];
    } else {
        float a0 = 0.f, a1 = 0.f, a2 = 0.f, a3 = 0.f;
        #pragma unroll
        for (int d = 0; d < C; d += 4) {
            a0 = fmaf(xp[d + 0], xp[d + 0], a0);
            a1 = fmaf(xp[d + 1], xp[d + 1], a1);
            a2 = fmaf(xp[d + 2], xp[d + 2], a2);
            a3 = fmaf(xp[d + 3], xp[d + 3], a3);
        }
        s = (a0 + a1) + (a2 + a3);
    }
    sq[p] = s;
}

// ---------------- knn: thread = point i, scan all j with uniform loads ----------------
template<int C>
__global__ __launch_bounds__(64) void knn_kernel(const float* __restrict__ pts,
                                                 const float* __restrict__ sq,
                                                 int* __restrict__ idx_out) {
    int b  = blockIdx.x >> 4;                       // 16 blocks (of 64 thr) per batch
    int il = ((blockIdx.x & 15) << 6) + threadIdx.x; // 0..1023
    int i  = (b << 10) + il;
    const float* base = pts + ((size_t)(b << 10)) * C;
    float xi[C];
    #pragma unroll
    for (int d = 0; d < C; ++d) xi[d] = base[(size_t)il * C + d];
    float sqi = sq[i];
    const float* sqb = sq + (b << 10);

    float bd[KNB]; int bj[KNB];
    #pragma unroll
    for (int k = 0; k < KNB; ++k) { bd[k] = 3.0e38f; bj[k] = 0; }

    #pragma unroll 2
    for (int j = 0; j < NPTS; ++j) {
        float dot;
        if constexpr (C == 1) {
            dot = xi[0] * base[j];
        } else {
            float a0 = 0.f, a1 = 0.f, a2 = 0.f, a3 = 0.f;
            #pragma unroll
            for (int d = 0; d < C; d += 4) {
                a0 = fmaf(xi[d + 0], base[(size_t)j * C + d + 0], a0);
                a1 = fmaf(xi[d + 1], base[(size_t)j * C + d + 1], a1);
                a2 = fmaf(xi[d + 2], base[(size_t)j * C + d + 2], a2);
                a3 = fmaf(xi[d + 3], base[(size_t)j * C + d + 3], a3);
            }
            dot = (a0 + a1) + (a2 + a3);
        }
        float dist = sqi + sqb[j] - 2.0f * dot;
        if (dist < bd[KNB - 1]) {
            bd[KNB - 1] = dist; bj[KNB - 1] = j;
            #pragma unroll
            for (int k = KNB - 1; k > 0; --k) {
                if (bd[k] < bd[k - 1]) {
                    float td = bd[k]; bd[k] = bd[k - 1]; bd[k - 1] = td;
                    int   tj = bj[k]; bj[k] = bj[k - 1]; bj[k - 1] = tj;
                }
            }
        }
    }
    int* op = idx_out + (size_t)i * KNB;
    #pragma unroll
    for (int k = 0; k < KNB; ++k) op[k] = bj[k];
}

// ---------------- u = x@(w1a-w1b)+b1 ; v = x@w1b  (factorized first MLP) ----------------
template<int CIN>
__global__ __launch_bounds__(256) void uv_kernel(const float* __restrict__ x,
                                                 const float* __restrict__ w1,
                                                 const float* __restrict__ b1,
                                                 float* __restrict__ u,
                                                 float* __restrict__ v) {
    int p = blockIdx.x * 256 + threadIdx.x;
    float xi[CIN];
    #pragma unroll
    for (int d = 0; d < CIN; ++d) xi[d] = x[(size_t)p * CIN + d];
    for (int o = 0; o < 64; ++o) {
        float ua0 = b1[o], ua1 = 0.f, vb0 = 0.f, vb1 = 0.f;
        if constexpr (CIN == 1) {
            float wa = w1[o], wb = w1[64 + o];
            ua0 = fmaf(xi[0], wa - wb, ua0);
            vb0 = xi[0] * wb;
        } else {
            #pragma unroll
            for (int d = 0; d < CIN; d += 2) {
                float wa0 = w1[(d + 0) * 64 + o];
                float wb0 = w1[(CIN + d + 0) * 64 + o];
                float wa1 = w1[(d + 1) * 64 + o];
                float wb1 = w1[(CIN + d + 1) * 64 + o];
                ua0 = fmaf(xi[d + 0], wa0 - wb0, ua0);
                vb0 = fmaf(xi[d + 0], wb0, vb0);
                ua1 = fmaf(xi[d + 1], wa1 - wb1, ua1);
                vb1 = fmaf(xi[d + 1], wb1, vb1);
            }
        }
        u[(size_t)p * 64 + o] = ua0 + ua1;
        v[(size_t)p * 64 + o] = vb0 + vb1;
    }
}

// ---------------- edge: h2 = relu(u_i+v_j)@w2+b2, max over 16 neighbors ----------------
__global__ __launch_bounds__(256) void edge_kernel(const float* __restrict__ u,
                                                   const float* __restrict__ v,
                                                   const int* __restrict__ idx,
                                                   const float* __restrict__ w2,
                                                   const float* __restrict__ b2,
                                                   float* __restrict__ out) {
    __shared__ float h1buf[4][KNB * 64];
    int wave = threadIdx.x >> 6, lane = threadIdx.x & 63;
    float w2col[64];
    #pragma unroll
    for (int c = 0; c < 64; ++c) w2col[c] = w2[c * 64 + lane]; // lane holds column `lane`
    float bias = b2[lane];
    int gw = blockIdx.x * 4 + wave;                 // grid = 1024 blocks -> 4096 waves
    for (int p = gw; p < NPOINTS; p += 4096) {      // 16 uniform iterations per wave
        int b = p >> 10;
        float uc = u[(size_t)p * 64 + lane];
        const int* ip = idx + (size_t)p * KNB;
        #pragma unroll
        for (int k = 0; k < KNB; ++k) {
            int j = ip[k];
            float vc = v[((size_t)(b << 10) + j) * 64 + lane];
            float h = uc + vc;
            h1buf[wave][k * 64 + lane] = h > 0.f ? h : 0.f;
        }
        __syncthreads();
        float best = -3.0e38f;
        #pragma unroll 4
        for (int k = 0; k < KNB; ++k) {
            float acc = bias;
            #pragma unroll
            for (int c = 0; c < 64; c += 4) {
                const float4 h4 = *(const float4*)&h1buf[wave][k * 64 + c];
                acc = fmaf(h4.x, w2col[c + 0], acc);
                acc = fmaf(h4.y, w2col[c + 1], acc);
                acc = fmaf(h4.z, w2col[c + 2], acc);
                acc = fmaf(h4.w, w2col[c + 3], acc);
            }
            best = fmaxf(best, acc);
        }
        out[(size_t)p * 64 + lane] = best;
        __syncthreads();
    }
}

// ---------------- final MLP 192->128->64->32->2 + log_softmax ----------------
__global__ __launch_bounds__(256) void mlp_kernel(const float* __restrict__ x1,
                                                  const float* __restrict__ x2,
                                                  const float* __restrict__ x3,
                                                  const float* __restrict__ mw1, const float* __restrict__ mb1,
                                                  const float* __restrict__ mw2, const float* __restrict__ mb2,
                                                  const float* __restrict__ mw3, const float* __restrict__ mb3,
                                                  const float* __restrict__ mw4, const float* __restrict__ mb4,
                                                  float* __restrict__ out) {
    __shared__ float abuf[4][192 * 4];
    __shared__ float h1b[4][128 * 4];
    __shared__ float h2b[4][64 * 4];
    __shared__ float h3b[4][32 * 4];
    __shared__ float zb[4][4][2];
    int wave = threadIdx.x >> 6, lane = threadIdx.x & 63;
    int gw = blockIdx.x * 4 + wave;                    // 4096 waves, 4 pts each iter
    for (int g = gw; g < NPOINTS / 4; g += 4096) {     // 4 uniform iterations
        int p0 = g * 4;
        #pragma unroll
        for (int q = 0; q < 4; ++q) {
            int p = p0 + q;
            abuf[wave][(lane) * 4 + q]       = x1[(size_t)p * 64 + lane];
            abuf[wave][(64 + lane) * 4 + q]  = x2[(size_t)p * 64 + lane];
            abuf[wave][(128 + lane) * 4 + q] = x3[(size_t)p * 64 + lane];
        }
        __syncthreads();
        // L1: 192 -> 128, lane covers o=lane and o=lane+64, 4 points
        float a1c[2][4];
        #pragma unroll
        for (int h = 0; h < 2; ++h) {
            float bb = mb1[lane + 64 * h];
            #pragma unroll
            for (int q = 0; q < 4; ++q) a1c[h][q] = bb;
        }
        #pragma unroll 4
        for (int d = 0; d < 192; ++d) {
            const float4 a4 = *(const float4*)&abuf[wave][d * 4];
            float w0 = mw1[d * 128 + lane];
            float w1_ = mw1[d * 128 + 64 + lane];
            a1c[0][0] = fmaf(a4.x, w0, a1c[0][0]);
            a1c[0][1] = fmaf(a4.y, w0, a1c[0][1]);
            a1c[0][2] = fmaf(a4.z, w0, a1c[0][2]);
            a1c[0][3] = fmaf(a4.w, w0, a1c[0][3]);
            a1c[1][0] = fmaf(a4.x, w1_, a1c[1][0]);
            a1c[1][1] = fmaf(a4.y, w1_, a1c[1][1]);
            a1c[1][2] = fmaf(a4.z, w1_, a1c[1][2]);
            a1c[1][3] = fmaf(a4.w, w1_, a1c[1][3]);
        }
        #pragma unroll
        for (int h = 0; h < 2; ++h)
            #pragma unroll
            for (int q = 0; q < 4; ++q)
                h1b[wave][(lane + 64 * h) * 4 + q] = fmaxf(a1c[h][q], 0.f);
        __syncthreads();
        // L2: 128 -> 64, o = lane
        float a2c[4];
        { float bb = mb2[lane];
          #pragma unroll
          for (int q = 0; q < 4; ++q) a2c[q] = bb; }
        #pragma unroll 4
        for (int d = 0; d < 128; ++d) {
            const float4 a4 = *(const float4*)&h1b[wave][d * 4];
            float w = mw2[d * 64 + lane];
            a2c[0] = fmaf(a4.x, w, a2c[0]);
            a2c[1] = fmaf(a4.y, w, a2c[1]);
            a2c[2] = fmaf(a4.z, w, a2c[2]);
            a2c[3] = fmaf(a4.w, w, a2c[3]);
        }
        #pragma unroll
        for (int q = 0; q < 4; ++q) h2b[wave][lane * 4 + q] = fmaxf(a2c[q], 0.f);
        __syncthreads();
        // L3: 64 -> 32, o = lane & 31 (x2 redundant)
        int o3 = lane & 31;
        float a3c[4];
        { float bb = mb3[o3];
          #pragma unroll
          for (int q = 0; q < 4; ++q) a3c[q] = bb; }
        #pragma unroll 4
        for (int d = 0; d < 64; ++d) {
            const float4 a4 = *(const float4*)&h2b[wave][d * 4];
            float w = mw3[d * 32 + o3];
            a3c[0] = fmaf(a4.x, w, a3c[0]);
            a3c[1] = fmaf(a4.y, w, a3c[1]);
            a3c[2] = fmaf(a4.z, w, a3c[2]);
            a3c[3] = fmaf(a4.w, w, a3c[3]);
        }
        if (lane < 32) {
            #pragma unroll
            for (int q = 0; q < 4; ++q) h3b[wave][o3 * 4 + q] = fmaxf(a3c[q], 0.f);
        }
        __syncthreads();
        // L4: 32 -> 2, o = lane & 1
        int o4 = lane & 1;
        float a4c[4];
        { float bb = mb4[o4];
          #pragma unroll
          for (int q = 0; q < 4; ++q) a4c[q] = bb; }
        #pragma unroll
        for (int d = 0; d < 32; ++d) {
            const float4 a4 = *(const float4*)&h3b[wave][d * 4];
            float w = mw4[d * 2 + o4];
            a4c[0] = fmaf(a4.x, w, a4c[0]);
            a4c[1] = fmaf(a4.y, w, a4c[1]);
            a4c[2] = fmaf(a4.z, w, a4c[2]);
            a4c[3] = fmaf(a4.w, w, a4c[3]);
        }
        if (lane < 2) {
            #pragma unroll
            for (int q = 0; q < 4; ++q) zb[wave][q][lane] = a4c[q];
        }
        __syncthreads();
        if (lane < 4) {
            int q = lane, p = p0 + q;
            float z0 = zb[wave][q][0], z1 = zb[wave][q][1];
            float m = fmaxf(z0, z1);
            float ls = m + logf(expf(z0 - m) + expf(z1 - m));
            out[(size_t)p * 2 + 0] = z0 - ls;
            out[(size_t)p * 2 + 1] = z1 - ls;
        }
        __syncthreads();  // WAR on abuf before next iteration
    }
}

extern "C" void kernel_launch(void* const* d_in, const int* in_sizes, int n_in,
                              void* d_out, int out_size, void* d_ws, size_t ws_size,
                              hipStream_t stream) {
    const float* x0   = (const float*)d_in[0];
    const float* c1w1 = (const float*)d_in[1];  const float* c1b1 = (const float*)d_in[2];
    const float* c1w2 = (const float*)d_in[3];  const float* c1b2 = (const float*)d_in[4];
    const float* c2w1 = (const float*)d_in[5];  const float* c2b1 = (const float*)d_in[6];
    const float* c2w2 = (const float*)d_in[7];  const float* c2b2 = (const float*)d_in[8];
    const float* c3w1 = (const float*)d_in[9];  const float* c3b1 = (const float*)d_in[10];
    const float* c3w2 = (const float*)d_in[11]; const float* c3b2 = (const float*)d_in[12];
    const float* mw1  = (const float*)d_in[13]; const float* mb1  = (const float*)d_in[14];
    const float* mw2  = (const float*)d_in[15]; const float* mb2  = (const float*)d_in[16];
    const float* mw3  = (const float*)d_in[17]; const float* mb3  = (const float*)d_in[18];
    const float* mw4  = (const float*)d_in[19]; const float* mb4  = (const float*)d_in[20];

    float* ws = (float*)d_ws;
    const size_t NF = (size_t)NPOINTS * 64;
    float* x1 = ws;
    float* x2 = x1 + NF;
    float* x3 = x2 + NF;
    float* u  = x3 + NF;
    float* v  = u  + NF;
    float* sq = v  + NF;
    int*  idx = (int*)(sq + NPOINTS);
    float* out = (float*)d_out;

    // ---- layer 1 (C_in = 1) ----
    sqnorm_kernel<1><<<NPOINTS / 64, 64, 0, stream>>>(x0, sq);
    knn_kernel<1><<<NPOINTS / 64, 64, 0, stream>>>(x0, sq, idx);
    uv_kernel<1><<<NPOINTS / 256, 256, 0, stream>>>(x0, c1w1, c1b1, u, v);
    edge_kernel<<<1024, 256, 0, stream>>>(u, v, idx, c1w2, c1b2, x1);
    // ---- layer 2 ----
    sqnorm_kernel<64><<<NPOINTS / 64, 64, 0, stream>>>(x1, sq);
    knn_kernel<64><<<NPOINTS / 64, 64, 0, stream>>>(x1, sq, idx);
    uv_kernel<64><<<NPOINTS / 256, 256, 0, stream>>>(x1, c2w1, c2b1, u, v);
    edge_kernel<<<1024, 256, 0, stream>>>(u, v, idx, c2w2, c2b2, x2);
    // ---- layer 3 ----
    sqnorm_kernel<64><<<NPOINTS / 64, 64, 0, stream>>>(x2, sq);
    knn_kernel<64><<<NPOINTS / 64, 64, 0, stream>>>(x2, sq, idx);
    uv_kernel<64><<<NPOINTS / 256, 256, 0, stream>>>(x2, c3w1, c3b1, u, v);
    edge_kernel<<<1024, 256, 0, stream>>>(u, v, idx, c3w2, c3b2, x3);
    // ---- final MLP + log_softmax ----
    mlp_kernel<<<1024, 256, 0, stream>>>(x1, x2, x3, mw1, mb1, mw2, mb2,
                                         mw3, mb3, mw4, mb4, out);
}

// Round 2
// 2904.038 us; speedup vs baseline: 1.4593x; 1.4593x over previous
//
#include <hip/hip_runtime.h>
#include <math.h>

static constexpr int NPTS = 1024;
static constexpr int NB = 64;
static constexpr int NPOINTS = NB * NPTS;   // 65536
static constexpr int KNB = 16;
static constexpr int NCHUNK = 4;            // j-range split for knn occupancy

// ---------------- squared norms (order must match knn dot chain) ----------------
template<int C>
__global__ __launch_bounds__(64) void sqnorm_kernel(const float* __restrict__ x,
                                                    float* __restrict__ sq) {
    int p = blockIdx.x * 64 + threadIdx.x;
    const float* xp = x + (size_t)p * C;
    float s;
    if constexpr (C == 1) {
        s = xp[0] * xp[0];
    } else {
        float a0 = 0.f, a1 = 0.f, a2 = 0.f, a3 = 0.f;
        #pragma unroll
        for (int d = 0; d < C; d += 4) {
            a0 = fmaf(xp[d + 0], xp[d + 0], a0);
            a1 = fmaf(xp[d + 1], xp[d + 1], a1);
            a2 = fmaf(xp[d + 2], xp[d + 2], a2);
            a3 = fmaf(xp[d + 3], xp[d + 3], a3);
        }
        s = (a0 + a1) + (a2 + a3);
    }
    sq[p] = s;
}

// ---------------- knn part: 1 wave = 64 i-points, scans one j-chunk via LDS tiles ----
// grid = (NPOINTS/64) * NCHUNK single-wave blocks -> 16 waves/CU available.
// Writes per-chunk top-16 candidates transposed: cand[(chunk*16+k)*NPOINTS + i]
// so both the write here and the read in merge are lane-coalesced.
template<int C>
__global__ __launch_bounds__(64) void knn_part_kernel(const float* __restrict__ pts,
                                                      const float* __restrict__ sq,
                                                      float* __restrict__ cand_d,
                                                      int* __restrict__ cand_j) {
    constexpr int JT = 32;                       // LDS tile: 32 j-points
    constexpr int JC = NPTS / NCHUNK;            // 256 j per chunk
    __shared__ float tile[JT * C];
    __shared__ float tsq[JT];
    int chunk = blockIdx.x & (NCHUNK - 1);
    int pblk  = blockIdx.x >> 2;
    int i  = pblk * 64 + threadIdx.x;
    int b  = i >> 10;
    int il = i & 1023;
    const float* base = pts + (size_t)(b << 10) * C;
    float xi[C];
    #pragma unroll
    for (int d = 0; d < C; ++d) xi[d] = base[(size_t)il * C + d];
    float sqi = sq[i];
    const float* sqb = sq + (b << 10);

    float bd[KNB]; int bj[KNB];
    #pragma unroll
    for (int k = 0; k < KNB; ++k) { bd[k] = 3.0e38f; bj[k] = 0; }

    int j0 = chunk * JC;
    for (int jt = 0; jt < JC; jt += JT) {
        // cooperative tile load (coalesced)
        const float* src = base + (size_t)(j0 + jt) * C;
        if constexpr (C >= 4) {
            #pragma unroll
            for (int t = threadIdx.x; t < JT * C / 4; t += 64)
                ((float4*)tile)[t] = ((const float4*)src)[t];
        } else {
            if (threadIdx.x < JT) tile[threadIdx.x] = src[threadIdx.x];
        }
        if (threadIdx.x < JT) tsq[threadIdx.x] = sqb[j0 + jt + threadIdx.x];
        __syncthreads();   // single-wave block: nearly free
        #pragma unroll 2
        for (int jj = 0; jj < JT; ++jj) {
            float dot;
            if constexpr (C == 1) {
                dot = xi[0] * tile[jj];
            } else {
                float a0 = 0.f, a1 = 0.f, a2 = 0.f, a3 = 0.f;
                #pragma unroll
                for (int d = 0; d < C; d += 4) {
                    const float4 t4 = *(const float4*)&tile[jj * C + d];
                    a0 = fmaf(xi[d + 0], t4.x, a0);
                    a1 = fmaf(xi[d + 1], t4.y, a1);
                    a2 = fmaf(xi[d + 2], t4.z, a2);
                    a3 = fmaf(xi[d + 3], t4.w, a3);
                }
                dot = (a0 + a1) + (a2 + a3);
            }
            float dist = sqi + tsq[jj] - 2.0f * dot;
            if (dist < bd[KNB - 1]) {
                int j = j0 + jt + jj;
                bd[KNB - 1] = dist; bj[KNB - 1] = j;
                #pragma unroll
                for (int k = KNB - 1; k > 0; --k) {
                    if (bd[k] < bd[k - 1]) {
                        float td = bd[k]; bd[k] = bd[k - 1]; bd[k - 1] = td;
                        int   tj = bj[k]; bj[k] = bj[k - 1]; bj[k - 1] = tj;
                    }
                }
            }
        }
        __syncthreads();
    }
    #pragma unroll
    for (int k = 0; k < KNB; ++k) {
        cand_d[(size_t)(chunk * KNB + k) * NPOINTS + i] = bd[k];
        cand_j[(size_t)(chunk * KNB + k) * NPOINTS + i] = bj[k];
    }
}

// ---------------- knn merge: 4x16 candidates -> final top-16 ----------------
// Chunks visited in ascending-j order, each internally sorted with stable ties,
// strict < insertion => identical neighbor SET as a full ascending-j scan.
__global__ __launch_bounds__(256) void knn_merge_kernel(const float* __restrict__ cand_d,
                                                        const int* __restrict__ cand_j,
                                                        int* __restrict__ idx_out) {
    int i = blockIdx.x * 256 + threadIdx.x;
    float bd[KNB]; int bj[KNB];
    #pragma unroll
    for (int k = 0; k < KNB; ++k) { bd[k] = 3.0e38f; bj[k] = 0; }
    #pragma unroll 4
    for (int t = 0; t < NCHUNK * KNB; ++t) {
        float d = cand_d[(size_t)t * NPOINTS + i];   // lane-coalesced
        int   j = cand_j[(size_t)t * NPOINTS + i];
        if (d < bd[KNB - 1]) {
            bd[KNB - 1] = d; bj[KNB - 1] = j;
            #pragma unroll
            for (int k = KNB - 1; k > 0; --k) {
                if (bd[k] < bd[k - 1]) {
                    float td = bd[k]; bd[k] = bd[k - 1]; bd[k - 1] = td;
                    int   tj = bj[k]; bj[k] = bj[k - 1]; bj[k - 1] = tj;
                }
            }
        }
    }
    int* op = idx_out + (size_t)i * KNB;
    #pragma unroll
    for (int k = 0; k < KNB; ++k) op[k] = bj[k];
}

// ---------------- u = x@(w1a-w1b)+b1 ; v = x@w1b  (factorized first MLP) ----------------
template<int CIN>
__global__ __launch_bounds__(64) void uv_kernel(const float* __restrict__ x,
                                                const float* __restrict__ w1,
                                                const float* __restrict__ b1,
                                                float* __restrict__ u,
                                                float* __restrict__ v) {
    int p = blockIdx.x * 64 + threadIdx.x;
    float xi[CIN];
    #pragma unroll
    for (int d = 0; d < CIN; ++d) xi[d] = x[(size_t)p * CIN + d];
    for (int o = 0; o < 64; ++o) {
        float ua0 = b1[o], ua1 = 0.f, vb0 = 0.f, vb1 = 0.f;
        if constexpr (CIN == 1) {
            float wa = w1[o], wb = w1[64 + o];
            ua0 = fmaf(xi[0], wa - wb, ua0);
            vb0 = xi[0] * wb;
        } else {
            #pragma unroll
            for (int d = 0; d < CIN; d += 2) {
                float wa0 = w1[(d + 0) * 64 + o];
                float wb0 = w1[(CIN + d + 0) * 64 + o];
                float wa1 = w1[(d + 1) * 64 + o];
                float wb1 = w1[(CIN + d + 1) * 64 + o];
                ua0 = fmaf(xi[d + 0], wa0 - wb0, ua0);
                vb0 = fmaf(xi[d + 0], wb0, vb0);
                ua1 = fmaf(xi[d + 1], wa1 - wb1, ua1);
                vb1 = fmaf(xi[d + 1], wb1, vb1);
            }
        }
        u[(size_t)p * 64 + o] = ua0 + ua1;
        v[(size_t)p * 64 + o] = vb0 + vb1;
    }
}

// ---------------- edge: h2 = relu(u_i+v_j)@w2+b2, max over 16 neighbors ----------------
// h1buf is wave-private -> NO __syncthreads needed (lgkmcnt ordering within wave).
__global__ __launch_bounds__(256) void edge_kernel(const float* __restrict__ u,
                                                   const float* __restrict__ v,
                                                   const int* __restrict__ idx,
                                                   const float* __restrict__ w2,
                                                   const float* __restrict__ b2,
                                                   float* __restrict__ out) {
    __shared__ float h1buf[4][KNB * 64];
    int wave = threadIdx.x >> 6, lane = threadIdx.x & 63;
    float w2col[64];
    #pragma unroll
    for (int c = 0; c < 64; ++c) w2col[c] = w2[c * 64 + lane]; // lane holds column `lane`
    float bias = b2[lane];
    int gw = blockIdx.x * 4 + wave;                 // grid = 2048 blocks -> 8192 waves
    for (int p = gw; p < NPOINTS; p += 8192) {      // 8 uniform iterations per wave
        int b = p >> 10;
        float uc = u[(size_t)p * 64 + lane];
        const int* ip = idx + (size_t)p * KNB;
        #pragma unroll
        for (int k = 0; k < KNB; ++k) {
            int j = ip[k];
            float vc = v[((size_t)(b << 10) + j) * 64 + lane];
            float h = uc + vc;
            h1buf[wave][k * 64 + lane] = h > 0.f ? h : 0.f;
        }
        float best = -3.0e38f;
        #pragma unroll 4
        for (int k = 0; k < KNB; ++k) {
            float acc = bias;
            #pragma unroll
            for (int c = 0; c < 64; c += 4) {
                const float4 h4 = *(const float4*)&h1buf[wave][k * 64 + c];
                acc = fmaf(h4.x, w2col[c + 0], acc);
                acc = fmaf(h4.y, w2col[c + 1], acc);
                acc = fmaf(h4.z, w2col[c + 2], acc);
                acc = fmaf(h4.w, w2col[c + 3], acc);
            }
            best = fmaxf(best, acc);
        }
        out[(size_t)p * 64 + lane] = best;
    }
}

// ---------------- final MLP 192->128->64->32->2 + log_softmax ----------------
// all LDS buffers wave-private -> no barriers.
__global__ __launch_bounds__(256) void mlp_kernel(const float* __restrict__ x1,
                                                  const float* __restrict__ x2,
                                                  const float* __restrict__ x3,
                                                  const float* __restrict__ mw1, const float* __restrict__ mb1,
                                                  const float* __restrict__ mw2, const float* __restrict__ mb2,
                                                  const float* __restrict__ mw3, const float* __restrict__ mb3,
                                                  const float* __restrict__ mw4, const float* __restrict__ mb4,
                                                  float* __restrict__ out) {
    __shared__ float abuf[4][192 * 4];
    __shared__ float h1b[4][128 * 4];
    __shared__ float h2b[4][64 * 4];
    __shared__ float h3b[4][32 * 4];
    __shared__ float zb[4][4][2];
    int wave = threadIdx.x >> 6, lane = threadIdx.x & 63;
    int gw = blockIdx.x * 4 + wave;                    // 4096 waves, 4 pts each iter
    for (int g = gw; g < NPOINTS / 4; g += 4096) {     // 4 uniform iterations
        int p0 = g * 4;
        #pragma unroll
        for (int q = 0; q < 4; ++q) {
            int p = p0 + q;
            abuf[wave][(lane) * 4 + q]       = x1[(size_t)p * 64 + lane];
            abuf[wave][(64 + lane) * 4 + q]  = x2[(size_t)p * 64 + lane];
            abuf[wave][(128 + lane) * 4 + q] = x3[(size_t)p * 64 + lane];
        }
        // L1: 192 -> 128, lane covers o=lane and o=lane+64, 4 points
        float a1c[2][4];
        #pragma unroll
        for (int h = 0; h < 2; ++h) {
            float bb = mb1[lane + 64 * h];
            #pragma unroll
            for (int q = 0; q < 4; ++q) a1c[h][q] = bb;
        }
        #pragma unroll 4
        for (int d = 0; d < 192; ++d) {
            const float4 a4 = *(const float4*)&abuf[wave][d * 4];
            float w0 = mw1[d * 128 + lane];
            float w1_ = mw1[d * 128 + 64 + lane];
            a1c[0][0] = fmaf(a4.x, w0, a1c[0][0]);
            a1c[0][1] = fmaf(a4.y, w0, a1c[0][1]);
            a1c[0][2] = fmaf(a4.z, w0, a1c[0][2]);
            a1c[0][3] = fmaf(a4.w, w0, a1c[0][3]);
            a1c[1][0] = fmaf(a4.x, w1_, a1c[1][0]);
            a1c[1][1] = fmaf(a4.y, w1_, a1c[1][1]);
            a1c[1][2] = fmaf(a4.z, w1_, a1c[1][2]);
            a1c[1][3] = fmaf(a4.w, w1_, a1c[1][3]);
        }
        #pragma unroll
        for (int h = 0; h < 2; ++h)
            #pragma unroll
            for (int q = 0; q < 4; ++q)
                h1b[wave][(lane + 64 * h) * 4 + q] = fmaxf(a1c[h][q], 0.f);
        // L2: 128 -> 64, o = lane
        float a2c[4];
        { float bb = mb2[lane];
          #pragma unroll
          for (int q = 0; q < 4; ++q) a2c[q] = bb; }
        #pragma unroll 4
        for (int d = 0; d < 128; ++d) {
            const float4 a4 = *(const float4*)&h1b[wave][d * 4];
            float w = mw2[d * 64 + lane];
            a2c[0] = fmaf(a4.x, w, a2c[0]);
            a2c[1] = fmaf(a4.y, w, a2c[1]);
            a2c[2] = fmaf(a4.z, w, a2c[2]);
            a2c[3] = fmaf(a4.w, w, a2c[3]);
        }
        #pragma unroll
        for (int q = 0; q < 4; ++q) h2b[wave][lane * 4 + q] = fmaxf(a2c[q], 0.f);
        // L3: 64 -> 32, o = lane & 31 (x2 redundant)
        int o3 = lane & 31;
        float a3c[4];
        { float bb = mb3[o3];
          #pragma unroll
          for (int q = 0; q < 4; ++q) a3c[q] = bb; }
        #pragma unroll 4
        for (int d = 0; d < 64; ++d) {
            const float4 a4 = *(const float4*)&h2b[wave][d * 4];
            float w = mw3[d * 32 + o3];
            a3c[0] = fmaf(a4.x, w, a3c[0]);
            a3c[1] = fmaf(a4.y, w, a3c[1]);
            a3c[2] = fmaf(a4.z, w, a3c[2]);
            a3c[3] = fmaf(a4.w, w, a3c[3]);
        }
        if (lane < 32) {
            #pragma unroll
            for (int q = 0; q < 4; ++q) h3b[wave][o3 * 4 + q] = fmaxf(a3c[q], 0.f);
        }
        // L4: 32 -> 2, o = lane & 1
        int o4 = lane & 1;
        float a4c[4];
        { float bb = mb4[o4];
          #pragma unroll
          for (int q = 0; q < 4; ++q) a4c[q] = bb; }
        #pragma unroll
        for (int d = 0; d < 32; ++d) {
            const float4 a4 = *(const float4*)&h3b[wave][d * 4];
            float w = mw4[d * 2 + o4];
            a4c[0] = fmaf(a4.x, w, a4c[0]);
            a4c[1] = fmaf(a4.y, w, a4c[1]);
            a4c[2] = fmaf(a4.z, w, a4c[2]);
            a4c[3] = fmaf(a4.w, w, a4c[3]);
        }
        if (lane < 2) {
            #pragma unroll
            for (int q = 0; q < 4; ++q) zb[wave][q][lane] = a4c[q];
        }
        if (lane < 4) {
            int q = lane, p = p0 + q;
            float z0 = zb[wave][q][0], z1 = zb[wave][q][1];
            float m = fmaxf(z0, z1);
            float ls = m + logf(expf(z0 - m) + expf(z1 - m));
            out[(size_t)p * 2 + 0] = z0 - ls;
            out[(size_t)p * 2 + 1] = z1 - ls;
        }
    }
}

extern "C" void kernel_launch(void* const* d_in, const int* in_sizes, int n_in,
                              void* d_out, int out_size, void* d_ws, size_t ws_size,
                              hipStream_t stream) {
    const float* x0   = (const float*)d_in[0];
    const float* c1w1 = (const float*)d_in[1];  const float* c1b1 = (const float*)d_in[2];
    const float* c1w2 = (const float*)d_in[3];  const float* c1b2 = (const float*)d_in[4];
    const float* c2w1 = (const float*)d_in[5];  const float* c2b1 = (const float*)d_in[6];
    const float* c2w2 = (const float*)d_in[7];  const float* c2b2 = (const float*)d_in[8];
    const float* c3w1 = (const float*)d_in[9];  const float* c3b1 = (const float*)d_in[10];
    const float* c3w2 = (const float*)d_in[11]; const float* c3b2 = (const float*)d_in[12];
    const float* mw1  = (const float*)d_in[13]; const float* mb1  = (const float*)d_in[14];
    const float* mw2  = (const float*)d_in[15]; const float* mb2  = (const float*)d_in[16];
    const float* mw3  = (const float*)d_in[17]; const float* mb3  = (const float*)d_in[18];
    const float* mw4  = (const float*)d_in[19]; const float* mb4  = (const float*)d_in[20];

    float* ws = (float*)d_ws;
    const size_t NF = (size_t)NPOINTS * 64;
    float* x1 = ws;
    float* x2 = x1 + NF;
    float* x3 = x2 + NF;
    float* u  = x3 + NF;
    float* v  = u  + NF;
    float* sq = v  + NF;
    int*  idx = (int*)(sq + NPOINTS);
    // cand buffers are only live between knn_part and knn_merge; u/v are only
    // live from uv_kernel to edge_kernel -> safe to alias (stream-ordered).
    float* cand_d = u;
    int*   cand_j = (int*)v;
    float* out = (float*)d_out;

    const int knn_grid = (NPOINTS / 64) * NCHUNK;   // 4096 single-wave blocks

    // ---- layer 1 (C_in = 1) ----
    sqnorm_kernel<1><<<NPOINTS / 64, 64, 0, stream>>>(x0, sq);
    knn_part_kernel<1><<<knn_grid, 64, 0, stream>>>(x0, sq, cand_d, cand_j);
    knn_merge_kernel<<<NPOINTS / 256, 256, 0, stream>>>(cand_d, cand_j, idx);
    uv_kernel<1><<<NPOINTS / 64, 64, 0, stream>>>(x0, c1w1, c1b1, u, v);
    edge_kernel<<<2048, 256, 0, stream>>>(u, v, idx, c1w2, c1b2, x1);
    // ---- layer 2 ----
    sqnorm_kernel<64><<<NPOINTS / 64, 64, 0, stream>>>(x1, sq);
    knn_part_kernel<64><<<knn_grid, 64, 0, stream>>>(x1, sq, cand_d, cand_j);
    knn_merge_kernel<<<NPOINTS / 256, 256, 0, stream>>>(cand_d, cand_j, idx);
    uv_kernel<64><<<NPOINTS / 64, 64, 0, stream>>>(x1, c2w1, c2b1, u, v);
    edge_kernel<<<2048, 256, 0, stream>>>(u, v, idx, c2w2, c2b2, x2);
    // ---- layer 3 ----
    sqnorm_kernel<64><<<NPOINTS / 64, 64, 0, stream>>>(x2, sq);
    knn_part_kernel<64><<<knn_grid, 64, 0, stream>>>(x2, sq, cand_d, cand_j);
    knn_merge_kernel<<<NPOINTS / 256, 256, 0, stream>>>(cand_d, cand_j, idx);
    uv_kernel<64><<<NPOINTS / 64, 64, 0, stream>>>(x2, c3w1, c3b1, u, v);
    edge_kernel<<<2048, 256, 0, stream>>>(u, v, idx, c3w2, c3b2, x3);
    // ---- final MLP + log_softmax ----
    mlp_kernel<<<1024, 256, 0, stream>>>(x1, x2, x3, mw1, mb1, mw2, mb2,
                                         mw3, mb3, mw4, mb4, out);
}

// Round 3
// 1529.831 us; speedup vs baseline: 2.7702x; 1.8983x over previous
//
#include <hip/hip_runtime.h>
#include <math.h>

static constexpr int NPTS = 1024;
static constexpr int NB = 64;
static constexpr int NPOINTS = NB * NPTS;   // 65536
static constexpr int KNB = 16;
static constexpr int NCHUNK = 4;            // j-range split for knn occupancy

// ---------------- squared norms (order must match knn dot chain) ----------------
template<int C>
__global__ __launch_bounds__(64) void sqnorm_kernel(const float* __restrict__ x,
                                                    float* __restrict__ sq) {
    int p = blockIdx.x * 64 + threadIdx.x;
    const float* xp = x + (size_t)p * C;
    float s;
    if constexpr (C == 1) {
        s = xp[0] * xp[0];
    } else {
        float a0 = 0.f, a1 = 0.f, a2 = 0.f, a3 = 0.f;
        #pragma unroll
        for (int d = 0; d < C; d += 4) {
            a0 = fmaf(xp[d + 0], xp[d + 0], a0);
            a1 = fmaf(xp[d + 1], xp[d + 1], a1);
            a2 = fmaf(xp[d + 2], xp[d + 2], a2);
            a3 = fmaf(xp[d + 3], xp[d + 3], a3);
        }
        s = (a0 + a1) + (a2 + a3);
    }
    sq[p] = s;
}

// ---------------- knn part: 1 wave = 64 i-points, scans one j-chunk via LDS tiles ----
template<int C>
__global__ __launch_bounds__(64) void knn_part_kernel(const float* __restrict__ pts,
                                                      const float* __restrict__ sq,
                                                      float* __restrict__ cand_d,
                                                      int* __restrict__ cand_j) {
    constexpr int JT = 32;                       // LDS tile: 32 j-points
    constexpr int JC = NPTS / NCHUNK;            // 256 j per chunk
    __shared__ float tile[JT * C];
    __shared__ float tsq[JT];
    int chunk = blockIdx.x & (NCHUNK - 1);
    int pblk  = blockIdx.x >> 2;
    int i  = pblk * 64 + threadIdx.x;
    int b  = i >> 10;
    int il = i & 1023;
    const float* base = pts + (size_t)(b << 10) * C;
    float xi[C];
    #pragma unroll
    for (int d = 0; d < C; ++d) xi[d] = base[(size_t)il * C + d];
    float sqi = sq[i];
    const float* sqb = sq + (b << 10);

    float bd[KNB]; int bj[KNB];
    #pragma unroll
    for (int k = 0; k < KNB; ++k) { bd[k] = 3.0e38f; bj[k] = 0; }

    int j0 = chunk * JC;
    for (int jt = 0; jt < JC; jt += JT) {
        const float* src = base + (size_t)(j0 + jt) * C;
        if constexpr (C >= 4) {
            #pragma unroll
            for (int t = threadIdx.x; t < JT * C / 4; t += 64)
                ((float4*)tile)[t] = ((const float4*)src)[t];
        } else {
            if (threadIdx.x < JT) tile[threadIdx.x] = src[threadIdx.x];
        }
        if (threadIdx.x < JT) tsq[threadIdx.x] = sqb[j0 + jt + threadIdx.x];
        __syncthreads();
        #pragma unroll 2
        for (int jj = 0; jj < JT; ++jj) {
            float dot;
            if constexpr (C == 1) {
                dot = xi[0] * tile[jj];
            } else {
                float a0 = 0.f, a1 = 0.f, a2 = 0.f, a3 = 0.f;
                #pragma unroll
                for (int d = 0; d < C; d += 4) {
                    const float4 t4 = *(const float4*)&tile[jj * C + d];
                    a0 = fmaf(xi[d + 0], t4.x, a0);
                    a1 = fmaf(xi[d + 1], t4.y, a1);
                    a2 = fmaf(xi[d + 2], t4.z, a2);
                    a3 = fmaf(xi[d + 3], t4.w, a3);
                }
                dot = (a0 + a1) + (a2 + a3);
            }
            float dist = sqi + tsq[jj] - 2.0f * dot;
            if (dist < bd[KNB - 1]) {
                int j = j0 + jt + jj;
                bd[KNB - 1] = dist; bj[KNB - 1] = j;
                #pragma unroll
                for (int k = KNB - 1; k > 0; --k) {
                    if (bd[k] < bd[k - 1]) {
                        float td = bd[k]; bd[k] = bd[k - 1]; bd[k - 1] = td;
                        int   tj = bj[k]; bj[k] = bj[k - 1]; bj[k - 1] = tj;
                    }
                }
            }
        }
        __syncthreads();
    }
    #pragma unroll
    for (int k = 0; k < KNB; ++k) {
        cand_d[(size_t)(chunk * KNB + k) * NPOINTS + i] = bd[k];
        cand_j[(size_t)(chunk * KNB + k) * NPOINTS + i] = bj[k];
    }
}

// ---------------- knn merge: 4x16 candidates -> final top-16 ----------------
__global__ __launch_bounds__(256) void knn_merge_kernel(const float* __restrict__ cand_d,
                                                        const int* __restrict__ cand_j,
                                                        int* __restrict__ idx_out) {
    int i = blockIdx.x * 256 + threadIdx.x;
    float bd[KNB]; int bj[KNB];
    #pragma unroll
    for (int k = 0; k < KNB; ++k) { bd[k] = 3.0e38f; bj[k] = 0; }
    #pragma unroll 4
    for (int t = 0; t < NCHUNK * KNB; ++t) {
        float d = cand_d[(size_t)t * NPOINTS + i];
        int   j = cand_j[(size_t)t * NPOINTS + i];
        if (d < bd[KNB - 1]) {
            bd[KNB - 1] = d; bj[KNB - 1] = j;
            #pragma unroll
            for (int k = KNB - 1; k > 0; --k) {
                if (bd[k] < bd[k - 1]) {
                    float td = bd[k]; bd[k] = bd[k - 1]; bd[k - 1] = td;
                    int   tj = bj[k]; bj[k] = bj[k - 1]; bj[k - 1] = tj;
                }
            }
        }
    }
    int* op = idx_out + (size_t)i * KNB;
    #pragma unroll
    for (int k = 0; k < KNB; ++k) op[k] = bj[k];
}

// ---------------- uv for layer 1 (C_in = 1): elementwise ----------------
__global__ __launch_bounds__(256) void uv1_kernel(const float* __restrict__ x,
                                                  const float* __restrict__ w1,
                                                  const float* __restrict__ b1,
                                                  float* __restrict__ u,
                                                  float* __restrict__ v) {
    int lane = threadIdx.x & 63, wave = threadIdx.x >> 6;
    float wa = w1[lane], wb = w1[64 + lane], bb = b1[lane];
    float wd = wa - wb;
    int gw = blockIdx.x * 4 + wave;                 // grid 1024 -> 4096 waves
    for (int p = gw; p < NPOINTS; p += 4096) {
        float xv = x[p];                            // wave-uniform -> scalar load
        u[(size_t)p * 64 + lane] = fmaf(xv, wd, bb);
        v[(size_t)p * 64 + lane] = xv * wb;
    }
}

// ---------------- uv GEMM (CIN=64): M=64 pts, N=128=[u|v], K=64 per block --------
__global__ __launch_bounds__(256) void uv_gemm_kernel(const float* __restrict__ x,
                                                      const float* __restrict__ w1,
                                                      const float* __restrict__ b1,
                                                      float* __restrict__ u,
                                                      float* __restrict__ v) {
    __shared__ float As[64 * 68];    // [c][p], stride 68 (16B-aligned rows, fewer conflicts)
    __shared__ float Bs[64 * 128];   // [c][o], o<64: w1a-w1b, o>=64: w1b
    int t = threadIdx.x;
    int p0 = blockIdx.x * 64;
    // stage B
    for (int g = t; g < 64 * 16; g += 256) {       // u-part
        int c = g >> 4, o4 = (g & 15) * 4;
        float4 wa = *(const float4*)&w1[c * 64 + o4];
        float4 wb = *(const float4*)&w1[(64 + c) * 64 + o4];
        float4 d; d.x = wa.x - wb.x; d.y = wa.y - wb.y; d.z = wa.z - wb.z; d.w = wa.w - wb.w;
        *(float4*)&Bs[c * 128 + o4] = d;
    }
    for (int g = t; g < 64 * 16; g += 256) {       // v-part
        int c = g >> 4, o4 = (g & 15) * 4;
        *(float4*)&Bs[c * 128 + 64 + o4] = *(const float4*)&w1[(64 + c) * 64 + o4];
    }
    // stage A via register 4x4 transpose: thread = (pq, cq), 16x16
    {
        int pq = t >> 4, cq = t & 15;
        const float* xp = x + (size_t)(p0 + pq * 4) * 64 + cq * 4;
        float4 r0 = *(const float4*)&xp[0 * 64];
        float4 r1 = *(const float4*)&xp[1 * 64];
        float4 r2 = *(const float4*)&xp[2 * 64];
        float4 r3 = *(const float4*)&xp[3 * 64];
        float4 c0; c0.x = r0.x; c0.y = r1.x; c0.z = r2.x; c0.w = r3.x;
        float4 c1; c1.x = r0.y; c1.y = r1.y; c1.z = r2.y; c1.w = r3.y;
        float4 c2; c2.x = r0.z; c2.y = r1.z; c2.z = r2.z; c2.w = r3.z;
        float4 c3; c3.x = r0.w; c3.y = r1.w; c3.z = r2.w; c3.w = r3.w;
        *(float4*)&As[(cq * 4 + 0) * 68 + pq * 4] = c0;
        *(float4*)&As[(cq * 4 + 1) * 68 + pq * 4] = c1;
        *(float4*)&As[(cq * 4 + 2) * 68 + pq * 4] = c2;
        *(float4*)&As[(cq * 4 + 3) * 68 + pq * 4] = c3;
    }
    __syncthreads();
    int rg = t >> 4;  // 4 points rg*4..+3
    int cg = t & 15;  // 8 outs cg*8..+7
    float acc[4][8];
    #pragma unroll
    for (int i = 0; i < 4; ++i)
        #pragma unroll
        for (int jj = 0; jj < 8; ++jj) acc[i][jj] = 0.f;
    #pragma unroll 4
    for (int c = 0; c < 64; ++c) {
        float4 a4 = *(const float4*)&As[c * 68 + rg * 4];
        float4 b0 = *(const float4*)&Bs[c * 128 + cg * 8];
        float4 b4 = *(const float4*)&Bs[c * 128 + cg * 8 + 4];
        float av[4] = {a4.x, a4.y, a4.z, a4.w};
        float bv[8] = {b0.x, b0.y, b0.z, b0.w, b4.x, b4.y, b4.z, b4.w};
        #pragma unroll
        for (int i = 0; i < 4; ++i)
            #pragma unroll
            for (int jj = 0; jj < 8; ++jj)
                acc[i][jj] = fmaf(av[i], bv[jj], acc[i][jj]);
    }
    if (cg < 8) {                                  // u-part, add bias
        float4 bb0 = *(const float4*)&b1[cg * 8];
        float4 bb1 = *(const float4*)&b1[cg * 8 + 4];
        #pragma unroll
        for (int i = 0; i < 4; ++i) {
            size_t p = p0 + rg * 4 + i;
            float4 o0; o0.x = acc[i][0] + bb0.x; o0.y = acc[i][1] + bb0.y;
                       o0.z = acc[i][2] + bb0.z; o0.w = acc[i][3] + bb0.w;
            float4 o1; o1.x = acc[i][4] + bb1.x; o1.y = acc[i][5] + bb1.y;
                       o1.z = acc[i][6] + bb1.z; o1.w = acc[i][7] + bb1.w;
            *(float4*)&u[p * 64 + cg * 8]     = o0;
            *(float4*)&u[p * 64 + cg * 8 + 4] = o1;
        }
    } else {
        int o = (cg - 8) * 8;
        #pragma unroll
        for (int i = 0; i < 4; ++i) {
            size_t p = p0 + rg * 4 + i;
            float4 o0; o0.x = acc[i][0]; o0.y = acc[i][1]; o0.z = acc[i][2]; o0.w = acc[i][3];
            float4 o1; o1.x = acc[i][4]; o1.y = acc[i][5]; o1.z = acc[i][6]; o1.w = acc[i][7];
            *(float4*)&v[p * 64 + o]     = o0;
            *(float4*)&v[p * 64 + o + 4] = o1;
        }
    }
}

// ---------------- edge GEMM: block = 4 points, A = relu(u_i+v_j) [64 rows x 64 c] ----
// rows = (p_loc<<4)|k; thread (r4,c4) computes 4x4; max over k = row-max + shfl_xor.
__global__ __launch_bounds__(256) void edge_kernel(const float* __restrict__ u,
                                                   const float* __restrict__ v,
                                                   const int* __restrict__ idx,
                                                   const float* __restrict__ w2,
                                                   const float* __restrict__ b2,
                                                   float* __restrict__ out) {
    __shared__ float As[64 * 64];   // [c][row]
    __shared__ float Bs[64 * 64];   // [c][o]
    int t = threadIdx.x;
    int p0 = blockIdx.x * 4;
    // stage w2 (already [c][o] row-major)
    #pragma unroll
    for (int g = t; g < 64 * 16; g += 256)
        *(float4*)&Bs[g * 4] = *(const float4*)&w2[g * 4];
    // build A: thread -> row r = t&63, channel-quad16 cq = t>>6
    {
        int r = t & 63, cq = t >> 6;
        int pl = r >> 4, k = r & 15;
        int p = p0 + pl;
        int b = p >> 10;
        int j = idx[p * 16 + k];
        const float* up = u + (size_t)p * 64 + cq * 16;
        const float* vp = v + ((size_t)(b << 10) + j) * 64 + cq * 16;
        #pragma unroll
        for (int q = 0; q < 4; ++q) {
            float4 uq = *(const float4*)&up[q * 4];
            float4 vq = *(const float4*)&vp[q * 4];
            int c = cq * 16 + q * 4;
            As[(c + 0) * 64 + r] = fmaxf(uq.x + vq.x, 0.f);
            As[(c + 1) * 64 + r] = fmaxf(uq.y + vq.y, 0.f);
            As[(c + 2) * 64 + r] = fmaxf(uq.z + vq.z, 0.f);
            As[(c + 3) * 64 + r] = fmaxf(uq.w + vq.w, 0.f);
        }
    }
    __syncthreads();
    int r4 = t >> 4;          // 4 rows r4*4..+3 (all k's of point r4>>2)
    int c4 = t & 15;          // 4 cols c4*4..+3
    float acc[4][4];
    #pragma unroll
    for (int i = 0; i < 4; ++i)
        #pragma unroll
        for (int jj = 0; jj < 4; ++jj) acc[i][jj] = 0.f;
    #pragma unroll 4
    for (int c = 0; c < 64; ++c) {
        float4 a4 = *(const float4*)&As[c * 64 + r4 * 4];
        float4 b4 = *(const float4*)&Bs[c * 64 + c4 * 4];
        float av[4] = {a4.x, a4.y, a4.z, a4.w};
        float bv[4] = {b4.x, b4.y, b4.z, b4.w};
        #pragma unroll
        for (int i = 0; i < 4; ++i)
            #pragma unroll
            for (int jj = 0; jj < 4; ++jj)
                acc[i][jj] = fmaf(av[i], bv[jj], acc[i][jj]);
    }
    // max over this thread's 4 rows (4 k's), then over the 4 r4-groups of the wave
    float m[4];
    #pragma unroll
    for (int jj = 0; jj < 4; ++jj)
        m[jj] = fmaxf(fmaxf(acc[0][jj], acc[1][jj]), fmaxf(acc[2][jj], acc[3][jj]));
    #pragma unroll
    for (int jj = 0; jj < 4; ++jj) {
        m[jj] = fmaxf(m[jj], __shfl_xor(m[jj], 16, 64));
        m[jj] = fmaxf(m[jj], __shfl_xor(m[jj], 32, 64));
    }
    int lane = t & 63;
    if (lane < 16) {
        int p = p0 + (t >> 6);                      // wave index = local point
        float4 bb = *(const float4*)&b2[lane * 4];
        float4 o4; o4.x = m[0] + bb.x; o4.y = m[1] + bb.y;
                   o4.z = m[2] + bb.z; o4.w = m[3] + bb.w;
        *(float4*)&out[(size_t)p * 64 + lane * 4] = o4;
    }
}

// ---------------- final MLP 192->128->64->32->2 + log_softmax ----------------
__global__ __launch_bounds__(256) void mlp_kernel(const float* __restrict__ x1,
                                                  const float* __restrict__ x2,
                                                  const float* __restrict__ x3,
                                                  const float* __restrict__ mw1, const float* __restrict__ mb1,
                                                  const float* __restrict__ mw2, const float* __restrict__ mb2,
                                                  const float* __restrict__ mw3, const float* __restrict__ mb3,
                                                  const float* __restrict__ mw4, const float* __restrict__ mb4,
                                                  float* __restrict__ out) {
    __shared__ float abuf[4][192 * 4];
    __shared__ float h1b[4][128 * 4];
    __shared__ float h2b[4][64 * 4];
    __shared__ float h3b[4][32 * 4];
    __shared__ float zb[4][4][2];
    int wave = threadIdx.x >> 6, lane = threadIdx.x & 63;
    int gw = blockIdx.x * 4 + wave;
    for (int g = gw; g < NPOINTS / 4; g += 4096) {
        int p0 = g * 4;
        #pragma unroll
        for (int q = 0; q < 4; ++q) {
            int p = p0 + q;
            abuf[wave][(lane) * 4 + q]       = x1[(size_t)p * 64 + lane];
            abuf[wave][(64 + lane) * 4 + q]  = x2[(size_t)p * 64 + lane];
            abuf[wave][(128 + lane) * 4 + q] = x3[(size_t)p * 64 + lane];
        }
        float a1c[2][4];
        #pragma unroll
        for (int h = 0; h < 2; ++h) {
            float bb = mb1[lane + 64 * h];
            #pragma unroll
            for (int q = 0; q < 4; ++q) a1c[h][q] = bb;
        }
        #pragma unroll 4
        for (int d = 0; d < 192; ++d) {
            const float4 a4 = *(const float4*)&abuf[wave][d * 4];
            float w0 = mw1[d * 128 + lane];
            float w1_ = mw1[d * 128 + 64 + lane];
            a1c[0][0] = fmaf(a4.x, w0, a1c[0][0]);
            a1c[0][1] = fmaf(a4.y, w0, a1c[0][1]);
            a1c[0][2] = fmaf(a4.z, w0, a1c[0][2]);
            a1c[0][3] = fmaf(a4.w, w0, a1c[0][3]);
            a1c[1][0] = fmaf(a4.x, w1_, a1c[1][0]);
            a1c[1][1] = fmaf(a4.y, w1_, a1c[1][1]);
            a1c[1][2] = fmaf(a4.z, w1_, a1c[1][2]);
            a1c[1][3] = fmaf(a4.w, w1_, a1c[1][3]);
        }
        #pragma unroll
        for (int h = 0; h < 2; ++h)
            #pragma unroll
            for (int q = 0; q < 4; ++q)
                h1b[wave][(lane + 64 * h) * 4 + q] = fmaxf(a1c[h][q], 0.f);
        float a2c[4];
        { float bb = mb2[lane];
          #pragma unroll
          for (int q = 0; q < 4; ++q) a2c[q] = bb; }
        #pragma unroll 4
        for (int d = 0; d < 128; ++d) {
            const float4 a4 = *(const float4*)&h1b[wave][d * 4];
            float w = mw2[d * 64 + lane];
            a2c[0] = fmaf(a4.x, w, a2c[0]);
            a2c[1] = fmaf(a4.y, w, a2c[1]);
            a2c[2] = fmaf(a4.z, w, a2c[2]);
            a2c[3] = fmaf(a4.w, w, a2c[3]);
        }
        #pragma unroll
        for (int q = 0; q < 4; ++q) h2b[wave][lane * 4 + q] = fmaxf(a2c[q], 0.f);
        int o3 = lane & 31;
        float a3c[4];
        { float bb = mb3[o3];
          #pragma unroll
          for (int q = 0; q < 4; ++q) a3c[q] = bb; }
        #pragma unroll 4
        for (int d = 0; d < 64; ++d) {
            const float4 a4 = *(const float4*)&h2b[wave][d * 4];
            float w = mw3[d * 32 + o3];
            a3c[0] = fmaf(a4.x, w, a3c[0]);
            a3c[1] = fmaf(a4.y, w, a3c[1]);
            a3c[2] = fmaf(a4.z, w, a3c[2]);
            a3c[3] = fmaf(a4.w, w, a3c[3]);
        }
        if (lane < 32) {
            #pragma unroll
            for (int q = 0; q < 4; ++q) h3b[wave][o3 * 4 + q] = fmaxf(a3c[q], 0.f);
        }
        int o4 = lane & 1;
        float a4c[4];
        { float bb = mb4[o4];
          #pragma unroll
          for (int q = 0; q < 4; ++q) a4c[q] = bb; }
        #pragma unroll
        for (int d = 0; d < 32; ++d) {
            const float4 a4 = *(const float4*)&h3b[wave][d * 4];
            float w = mw4[d * 2 + o4];
            a4c[0] = fmaf(a4.x, w, a4c[0]);
            a4c[1] = fmaf(a4.y, w, a4c[1]);
            a4c[2] = fmaf(a4.z, w, a4c[2]);
            a4c[3] = fmaf(a4.w, w, a4c[3]);
        }
        if (lane < 2) {
            #pragma unroll
            for (int q = 0; q < 4; ++q) zb[wave][q][lane] = a4c[q];
        }
        if (lane < 4) {
            int q = lane, p = p0 + q;
            float z0 = zb[wave][q][0], z1 = zb[wave][q][1];
            float m = fmaxf(z0, z1);
            float ls = m + logf(expf(z0 - m) + expf(z1 - m));
            out[(size_t)p * 2 + 0] = z0 - ls;
            out[(size_t)p * 2 + 1] = z1 - ls;
        }
    }
}

extern "C" void kernel_launch(void* const* d_in, const int* in_sizes, int n_in,
                              void* d_out, int out_size, void* d_ws, size_t ws_size,
                              hipStream_t stream) {
    const float* x0   = (const float*)d_in[0];
    const float* c1w1 = (const float*)d_in[1];  const float* c1b1 = (const float*)d_in[2];
    const float* c1w2 = (const float*)d_in[3];  const float* c1b2 = (const float*)d_in[4];
    const float* c2w1 = (const float*)d_in[5];  const float* c2b1 = (const float*)d_in[6];
    const float* c2w2 = (const float*)d_in[7];  const float* c2b2 = (const float*)d_in[8];
    const float* c3w1 = (const float*)d_in[9];  const float* c3b1 = (const float*)d_in[10];
    const float* c3w2 = (const float*)d_in[11]; const float* c3b2 = (const float*)d_in[12];
    const float* mw1  = (const float*)d_in[13]; const float* mb1  = (const float*)d_in[14];
    const float* mw2  = (const float*)d_in[15]; const float* mb2  = (const float*)d_in[16];
    const float* mw3  = (const float*)d_in[17]; const float* mb3  = (const float*)d_in[18];
    const float* mw4  = (const float*)d_in[19]; const float* mb4  = (const float*)d_in[20];

    float* ws = (float*)d_ws;
    const size_t NF = (size_t)NPOINTS * 64;
    float* x1 = ws;
    float* x2 = x1 + NF;
    float* x3 = x2 + NF;
    float* u  = x3 + NF;
    float* v  = u  + NF;
    float* sq = v  + NF;
    int*  idx = (int*)(sq + NPOINTS);
    float* cand_d = u;          // aliases: dead ranges don't overlap in time
    int*   cand_j = (int*)v;
    float* out = (float*)d_out;

    const int knn_grid = (NPOINTS / 64) * NCHUNK;   // 4096 single-wave blocks

    // ---- layer 1 (C_in = 1) ----
    sqnorm_kernel<1><<<NPOINTS / 64, 64, 0, stream>>>(x0, sq);
    knn_part_kernel<1><<<knn_grid, 64, 0, stream>>>(x0, sq, cand_d, cand_j);
    knn_merge_kernel<<<NPOINTS / 256, 256, 0, stream>>>(cand_d, cand_j, idx);
    uv1_kernel<<<1024, 256, 0, stream>>>(x0, c1w1, c1b1, u, v);
    edge_kernel<<<NPOINTS / 4, 256, 0, stream>>>(u, v, idx, c1w2, c1b2, x1);
    // ---- layer 2 ----
    sqnorm_kernel<64><<<NPOINTS / 64, 64, 0, stream>>>(x1, sq);
    knn_part_kernel<64><<<knn_grid, 64, 0, stream>>>(x1, sq, cand_d, cand_j);
    knn_merge_kernel<<<NPOINTS / 256, 256, 0, stream>>>(cand_d, cand_j, idx);
    uv_gemm_kernel<<<NPOINTS / 64, 256, 0, stream>>>(x1, c2w1, c2b1, u, v);
    edge_kernel<<<NPOINTS / 4, 256, 0, stream>>>(u, v, idx, c2w2, c2b2, x2);
    // ---- layer 3 ----
    sqnorm_kernel<64><<<NPOINTS / 64, 64, 0, stream>>>(x2, sq);
    knn_part_kernel<64><<<knn_grid, 64, 0, stream>>>(x2, sq, cand_d, cand_j);
    knn_merge_kernel<<<NPOINTS / 256, 256, 0, stream>>>(cand_d, cand_j, idx);
    uv_gemm_kernel<<<NPOINTS / 64, 256, 0, stream>>>(x2, c3w1, c3b1, u, v);
    edge_kernel<<<NPOINTS / 4, 256, 0, stream>>>(u, v, idx, c3w2, c3b2, x3);
    // ---- final MLP + log_softmax ----
    mlp_kernel<<<1024, 256, 0, stream>>>(x1, x2, x3, mw1, mb1, mw2, mb2,
                                         mw3, mb3, mw4, mb4, out);
}

// Round 4
// 1176.974 us; speedup vs baseline: 3.6007x; 1.2998x over previous
//
#include <hip/hip_runtime.h>
#include <math.h>

typedef unsigned short ushort_t;
typedef unsigned int uint_t;
typedef __bf16 bf16x8_t __attribute__((ext_vector_type(8)));
typedef float f32x4_t __attribute__((ext_vector_type(4)));

static constexpr int NPTS = 1024;
static constexpr int NB = 64;
static constexpr int NPOINTS = NB * NPTS;   // 65536
static constexpr int KNB = 16;
static constexpr int NCHUNK1 = 4;           // layer-1 fp32 knn chunking
static constexpr int NCHUNK2 = 2;           // mfma knn chunking

__device__ __forceinline__ ushort_t f2bf(float f) {
    uint_t u = __float_as_uint(f);
    uint_t r = (u + 0x7FFFu + ((u >> 16) & 1u)) >> 16;
    return (ushort_t)r;
}
__device__ __forceinline__ float bf2f(ushort_t h) {
    return __uint_as_float(((uint_t)h) << 16);
}

// ---------------- squared norms ----------------
template<int C>
__global__ __launch_bounds__(64) void sqnorm_kernel(const float* __restrict__ x,
                                                    float* __restrict__ sq) {
    int p = blockIdx.x * 64 + threadIdx.x;
    const float* xp = x + (size_t)p * C;
    float s;
    if constexpr (C == 1) {
        s = xp[0] * xp[0];
    } else {
        float a0 = 0.f, a1 = 0.f, a2 = 0.f, a3 = 0.f;
        #pragma unroll
        for (int d = 0; d < C; d += 4) {
            a0 = fmaf(xp[d + 0], xp[d + 0], a0);
            a1 = fmaf(xp[d + 1], xp[d + 1], a1);
            a2 = fmaf(xp[d + 2], xp[d + 2], a2);
            a3 = fmaf(xp[d + 3], xp[d + 3], a3);
        }
        s = (a0 + a1) + (a2 + a3);
    }
    sq[p] = s;
}

// ---------------- fp32 -> bf16 hi/lo split (for MFMA knn) ----------------
__global__ __launch_bounds__(256) void split_kernel(const float* __restrict__ x,
                                                    ushort_t* __restrict__ xh,
                                                    ushort_t* __restrict__ xl) {
    int t = threadIdx.x;
    int p = blockIdx.x * 64 + (t >> 2);
    int c0 = (t & 3) * 16;
    const float* xp = x + (size_t)p * 64 + c0;
    ushort_t h[16], l[16];
    #pragma unroll
    for (int q = 0; q < 16; ++q) {
        float f = xp[q];
        ushort_t hs = f2bf(f);
        h[q] = hs;
        l[q] = f2bf(f - bf2f(hs));
    }
    ushort_t* oh = xh + (size_t)p * 64 + c0;
    ushort_t* ol = xl + (size_t)p * 64 + c0;
    #pragma unroll
    for (int q = 0; q < 2; ++q) {
        ((uint4*)oh)[q] = ((const uint4*)h)[q];
        ((uint4*)ol)[q] = ((const uint4*)l)[q];
    }
}

// ---------------- layer-1 knn (C=1): fp32 LDS-tile scan ----------------
__global__ __launch_bounds__(64) void knn_part1_kernel(const float* __restrict__ pts,
                                                       const float* __restrict__ sq,
                                                       float* __restrict__ cand_d,
                                                       int* __restrict__ cand_j) {
    constexpr int JT = 32;
    constexpr int JC = NPTS / NCHUNK1;           // 256
    __shared__ float tile[JT];
    __shared__ float tsq[JT];
    int chunk = blockIdx.x & (NCHUNK1 - 1);
    int pblk  = blockIdx.x >> 2;
    int i  = pblk * 64 + threadIdx.x;
    int b  = i >> 10;
    int il = i & 1023;
    const float* base = pts + (size_t)(b << 10);
    float xi = base[il];
    float sqi = sq[i];
    const float* sqb = sq + (b << 10);

    float bd[KNB]; int bj[KNB];
    #pragma unroll
    for (int k = 0; k < KNB; ++k) { bd[k] = 3.0e38f; bj[k] = 0; }

    int j0 = chunk * JC;
    for (int jt = 0; jt < JC; jt += JT) {
        if (threadIdx.x < JT) {
            tile[threadIdx.x] = base[j0 + jt + threadIdx.x];
            tsq[threadIdx.x] = sqb[j0 + jt + threadIdx.x];
        }
        __syncthreads();
        #pragma unroll 2
        for (int jj = 0; jj < JT; ++jj) {
            float dot = xi * tile[jj];
            float dist = sqi + tsq[jj] - 2.0f * dot;
            if (dist < bd[KNB - 1]) {
                int j = j0 + jt + jj;
                bd[KNB - 1] = dist; bj[KNB - 1] = j;
                #pragma unroll
                for (int k = KNB - 1; k > 0; --k) {
                    if (bd[k] < bd[k - 1]) {
                        float td = bd[k]; bd[k] = bd[k - 1]; bd[k - 1] = td;
                        int   tj = bj[k]; bj[k] = bj[k - 1]; bj[k - 1] = tj;
                    }
                }
            }
        }
        __syncthreads();
    }
    #pragma unroll
    for (int k = 0; k < KNB; ++k) {
        cand_d[(size_t)(chunk * KNB + k) * NPOINTS + i] = bd[k];
        cand_j[(size_t)(chunk * KNB + k) * NPOINTS + i] = bj[k];
    }
}

// ---------------- MFMA knn (C=64): dist tiles via 16x16x32 bf16 hi/lo ----------------
// 1 wave = 64 i-points x 512 j (half). A-frags resident; per 16-j group:
// 24 MFMAs -> dist tile -> LDS [j][i] -> lane=i scans 16 j's into top-16 list.
__global__ __launch_bounds__(64, 2) void knn_mfma_kernel(const ushort_t* __restrict__ xh,
                                                         const ushort_t* __restrict__ xl,
                                                         const float* __restrict__ sq,
                                                         float* __restrict__ cand_d,
                                                         int* __restrict__ cand_j) {
    constexpr int JC = NPTS / NCHUNK2;           // 512
    __shared__ float dbuf[16 * 68];
    __shared__ float sqs[JC];
    int chunk = blockIdx.x & (NCHUNK2 - 1);
    int ib    = (blockIdx.x >> 1) & 15;
    int b     = blockIdx.x >> 5;
    int i0    = b * NPTS + ib * 64;
    int lane  = threadIdx.x;
    int m = lane & 15, quad = lane >> 4;
    int j0c = chunk * JC;

    for (int t = lane; t < JC; t += 64) sqs[t] = sq[b * NPTS + j0c + t];

    // A fragments: A[m=lane&15][k=quad*8+e], resident for 4 i-tiles x 2 K-halves x hi/lo
    bf16x8_t Ah[4][2], Al[4][2];
    #pragma unroll
    for (int it = 0; it < 4; ++it) {
        #pragma unroll
        for (int kh = 0; kh < 2; ++kh) {
            size_t off = ((size_t)(i0 + it * 16 + m)) * 64 + kh * 32 + quad * 8;
            Ah[it][kh] = *(const bf16x8_t*)(xh + off);
            Al[it][kh] = *(const bf16x8_t*)(xl + off);
        }
    }
    // sqi fragments: C-layout row = quad*4 + reg
    float4 sqi[4];
    #pragma unroll
    for (int it = 0; it < 4; ++it)
        sqi[it] = *(const float4*)&sq[i0 + it * 16 + quad * 4];

    float bd[KNB]; int bj[KNB];
    #pragma unroll
    for (int k = 0; k < KNB; ++k) { bd[k] = 3.0e38f; bj[k] = 0; }
    __syncthreads();

    for (int g = 0; g < JC / 16; ++g) {
        int jg = j0c + g * 16;                       // batch-local j base
        size_t boff = ((size_t)(b * NPTS + jg + m)) * 64 + quad * 8;
        bf16x8_t Bh0 = *(const bf16x8_t*)(xh + boff);
        bf16x8_t Bh1 = *(const bf16x8_t*)(xh + boff + 32);
        bf16x8_t Bl0 = *(const bf16x8_t*)(xl + boff);
        bf16x8_t Bl1 = *(const bf16x8_t*)(xl + boff + 32);
        float sqj = sqs[g * 16 + m];
        #pragma unroll
        for (int it = 0; it < 4; ++it) {
            f32x4_t acc = {0.f, 0.f, 0.f, 0.f};
            acc = __builtin_amdgcn_mfma_f32_16x16x32_bf16(Ah[it][0], Bh0, acc, 0, 0, 0);
            acc = __builtin_amdgcn_mfma_f32_16x16x32_bf16(Ah[it][1], Bh1, acc, 0, 0, 0);
            acc = __builtin_amdgcn_mfma_f32_16x16x32_bf16(Ah[it][0], Bl0, acc, 0, 0, 0);
            acc = __builtin_amdgcn_mfma_f32_16x16x32_bf16(Ah[it][1], Bl1, acc, 0, 0, 0);
            acc = __builtin_amdgcn_mfma_f32_16x16x32_bf16(Al[it][0], Bh0, acc, 0, 0, 0);
            acc = __builtin_amdgcn_mfma_f32_16x16x32_bf16(Al[it][1], Bh1, acc, 0, 0, 0);
            float4 dv;
            dv.x = sqi[it].x + sqj - 2.0f * acc[0];
            dv.y = sqi[it].y + sqj - 2.0f * acc[1];
            dv.z = sqi[it].z + sqj - 2.0f * acc[2];
            dv.w = sqi[it].w + sqj - 2.0f * acc[3];
            // dist(i_local = it*16 + quad*4 + r, j_local = m)
            *(float4*)&dbuf[m * 68 + it * 16 + quad * 4] = dv;
        }
        __syncthreads();
        #pragma unroll
        for (int jj = 0; jj < 16; ++jj) {
            float d = dbuf[jj * 68 + lane];
            if (d < bd[KNB - 1]) {
                int j = jg + jj;
                bd[KNB - 1] = d; bj[KNB - 1] = j;
                #pragma unroll
                for (int k = KNB - 1; k > 0; --k) {
                    if (bd[k] < bd[k - 1]) {
                        float td = bd[k]; bd[k] = bd[k - 1]; bd[k - 1] = td;
                        int   tj = bj[k]; bj[k] = bj[k - 1]; bj[k - 1] = tj;
                    }
                }
            }
        }
        __syncthreads();
    }
    #pragma unroll
    for (int k = 0; k < KNB; ++k) {
        cand_d[(size_t)(chunk * KNB + k) * NPOINTS + i0 + lane] = bd[k];
        cand_j[(size_t)(chunk * KNB + k) * NPOINTS + i0 + lane] = bj[k];
    }
}

// ---------------- knn merge: NC candidates -> final top-16 ----------------
template<int NC>
__global__ __launch_bounds__(256) void knn_merge_kernel(const float* __restrict__ cand_d,
                                                        const int* __restrict__ cand_j,
                                                        int* __restrict__ idx_out) {
    int i = blockIdx.x * 256 + threadIdx.x;
    float bd[KNB]; int bj[KNB];
    #pragma unroll
    for (int k = 0; k < KNB; ++k) { bd[k] = 3.0e38f; bj[k] = 0; }
    #pragma unroll 4
    for (int t = 0; t < NC; ++t) {
        float d = cand_d[(size_t)t * NPOINTS + i];
        int   j = cand_j[(size_t)t * NPOINTS + i];
        if (d < bd[KNB - 1]) {
            bd[KNB - 1] = d; bj[KNB - 1] = j;
            #pragma unroll
            for (int k = KNB - 1; k > 0; --k) {
                if (bd[k] < bd[k - 1]) {
                    float td = bd[k]; bd[k] = bd[k - 1]; bd[k - 1] = td;
                    int   tj = bj[k]; bj[k] = bj[k - 1]; bj[k - 1] = tj;
                }
            }
        }
    }
    int* op = idx_out + (size_t)i * KNB;
    #pragma unroll
    for (int k = 0; k < KNB; ++k) op[k] = bj[k];
}

// ---------------- uv for layer 1 (C_in = 1): elementwise ----------------
__global__ __launch_bounds__(256) void uv1_kernel(const float* __restrict__ x,
                                                  const float* __restrict__ w1,
                                                  const float* __restrict__ b1,
                                                  float* __restrict__ u,
                                                  float* __restrict__ v) {
    int lane = threadIdx.x & 63, wave = threadIdx.x >> 6;
    float wa = w1[lane], wb = w1[64 + lane], bb = b1[lane];
    float wd = wa - wb;
    int gw = blockIdx.x * 4 + wave;
    for (int p = gw; p < NPOINTS; p += 4096) {
        float xv = x[p];
        u[(size_t)p * 64 + lane] = fmaf(xv, wd, bb);
        v[(size_t)p * 64 + lane] = xv * wb;
    }
}

// ---------------- uv GEMM (CIN=64) ----------------
__global__ __launch_bounds__(256) void uv_gemm_kernel(const float* __restrict__ x,
                                                      const float* __restrict__ w1,
                                                      const float* __restrict__ b1,
                                                      float* __restrict__ u,
                                                      float* __restrict__ v) {
    __shared__ float As[64 * 68];
    __shared__ float Bs[64 * 128];
    int t = threadIdx.x;
    int p0 = blockIdx.x * 64;
    for (int g = t; g < 64 * 16; g += 256) {
        int c = g >> 4, o4 = (g & 15) * 4;
        float4 wa = *(const float4*)&w1[c * 64 + o4];
        float4 wb = *(const float4*)&w1[(64 + c) * 64 + o4];
        float4 d; d.x = wa.x - wb.x; d.y = wa.y - wb.y; d.z = wa.z - wb.z; d.w = wa.w - wb.w;
        *(float4*)&Bs[c * 128 + o4] = d;
    }
    for (int g = t; g < 64 * 16; g += 256) {
        int c = g >> 4, o4 = (g & 15) * 4;
        *(float4*)&Bs[c * 128 + 64 + o4] = *(const float4*)&w1[(64 + c) * 64 + o4];
    }
    {
        int pq = t >> 4, cq = t & 15;
        const float* xp = x + (size_t)(p0 + pq * 4) * 64 + cq * 4;
        float4 r0 = *(const float4*)&xp[0 * 64];
        float4 r1 = *(const float4*)&xp[1 * 64];
        float4 r2 = *(const float4*)&xp[2 * 64];
        float4 r3 = *(const float4*)&xp[3 * 64];
        float4 c0; c0.x = r0.x; c0.y = r1.x; c0.z = r2.x; c0.w = r3.x;
        float4 c1; c1.x = r0.y; c1.y = r1.y; c1.z = r2.y; c1.w = r3.y;
        float4 c2; c2.x = r0.z; c2.y = r1.z; c2.z = r2.z; c2.w = r3.z;
        float4 c3; c3.x = r0.w; c3.y = r1.w; c3.z = r2.w; c3.w = r3.w;
        *(float4*)&As[(cq * 4 + 0) * 68 + pq * 4] = c0;
        *(float4*)&As[(cq * 4 + 1) * 68 + pq * 4] = c1;
        *(float4*)&As[(cq * 4 + 2) * 68 + pq * 4] = c2;
        *(float4*)&As[(cq * 4 + 3) * 68 + pq * 4] = c3;
    }
    __syncthreads();
    int rg = t >> 4;
    int cg = t & 15;
    float acc[4][8];
    #pragma unroll
    for (int i = 0; i < 4; ++i)
        #pragma unroll
        for (int jj = 0; jj < 8; ++jj) acc[i][jj] = 0.f;
    #pragma unroll 4
    for (int c = 0; c < 64; ++c) {
        float4 a4 = *(const float4*)&As[c * 68 + rg * 4];
        float4 b0 = *(const float4*)&Bs[c * 128 + cg * 8];
        float4 b4 = *(const float4*)&Bs[c * 128 + cg * 8 + 4];
        float av[4] = {a4.x, a4.y, a4.z, a4.w};
        float bv[8] = {b0.x, b0.y, b0.z, b0.w, b4.x, b4.y, b4.z, b4.w};
        #pragma unroll
        for (int i = 0; i < 4; ++i)
            #pragma unroll
            for (int jj = 0; jj < 8; ++jj)
                acc[i][jj] = fmaf(av[i], bv[jj], acc[i][jj]);
    }
    if (cg < 8) {
        float4 bb0 = *(const float4*)&b1[cg * 8];
        float4 bb1 = *(const float4*)&b1[cg * 8 + 4];
        #pragma unroll
        for (int i = 0; i < 4; ++i) {
            size_t p = p0 + rg * 4 + i;
            float4 o0; o0.x = acc[i][0] + bb0.x; o0.y = acc[i][1] + bb0.y;
                       o0.z = acc[i][2] + bb0.z; o0.w = acc[i][3] + bb0.w;
            float4 o1; o1.x = acc[i][4] + bb1.x; o1.y = acc[i][5] + bb1.y;
                       o1.z = acc[i][6] + bb1.z; o1.w = acc[i][7] + bb1.w;
            *(float4*)&u[p * 64 + cg * 8]     = o0;
            *(float4*)&u[p * 64 + cg * 8 + 4] = o1;
        }
    } else {
        int o = (cg - 8) * 8;
        #pragma unroll
        for (int i = 0; i < 4; ++i) {
            size_t p = p0 + rg * 4 + i;
            float4 o0; o0.x = acc[i][0]; o0.y = acc[i][1]; o0.z = acc[i][2]; o0.w = acc[i][3];
            float4 o1; o1.x = acc[i][4]; o1.y = acc[i][5]; o1.z = acc[i][6]; o1.w = acc[i][7];
            *(float4*)&v[p * 64 + o]     = o0;
            *(float4*)&v[p * 64 + o + 4] = o1;
        }
    }
}

// ---------------- edge GEMM ----------------
__global__ __launch_bounds__(256) void edge_kernel(const float* __restrict__ u,
                                                   const float* __restrict__ v,
                                                   const int* __restrict__ idx,
                                                   const float* __restrict__ w2,
                                                   const float* __restrict__ b2,
                                                   float* __restrict__ out) {
    __shared__ float As[64 * 64];
    __shared__ float Bs[64 * 64];
    int t = threadIdx.x;
    int p0 = blockIdx.x * 4;
    #pragma unroll
    for (int g = t; g < 64 * 16; g += 256)
        *(float4*)&Bs[g * 4] = *(const float4*)&w2[g * 4];
    {
        int r = t & 63, cq = t >> 6;
        int pl = r >> 4, k = r & 15;
        int p = p0 + pl;
        int b = p >> 10;
        int j = idx[p * 16 + k];
        const float* up = u + (size_t)p * 64 + cq * 16;
        const float* vp = v + ((size_t)(b << 10) + j) * 64 + cq * 16;
        #pragma unroll
        for (int q = 0; q < 4; ++q) {
            float4 uq = *(const float4*)&up[q * 4];
            float4 vq = *(const float4*)&vp[q * 4];
            int c = cq * 16 + q * 4;
            As[(c + 0) * 64 + r] = fmaxf(uq.x + vq.x, 0.f);
            As[(c + 1) * 64 + r] = fmaxf(uq.y + vq.y, 0.f);
            As[(c + 2) * 64 + r] = fmaxf(uq.z + vq.z, 0.f);
            As[(c + 3) * 64 + r] = fmaxf(uq.w + vq.w, 0.f);
        }
    }
    __syncthreads();
    int r4 = t >> 4;
    int c4 = t & 15;
    float acc[4][4];
    #pragma unroll
    for (int i = 0; i < 4; ++i)
        #pragma unroll
        for (int jj = 0; jj < 4; ++jj) acc[i][jj] = 0.f;
    #pragma unroll 4
    for (int c = 0; c < 64; ++c) {
        float4 a4 = *(const float4*)&As[c * 64 + r4 * 4];
        float4 b4 = *(const float4*)&Bs[c * 64 + c4 * 4];
        float av[4] = {a4.x, a4.y, a4.z, a4.w};
        float bv[4] = {b4.x, b4.y, b4.z, b4.w};
        #pragma unroll
        for (int i = 0; i < 4; ++i)
            #pragma unroll
            for (int jj = 0; jj < 4; ++jj)
                acc[i][jj] = fmaf(av[i], bv[jj], acc[i][jj]);
    }
    float m[4];
    #pragma unroll
    for (int jj = 0; jj < 4; ++jj)
        m[jj] = fmaxf(fmaxf(acc[0][jj], acc[1][jj]), fmaxf(acc[2][jj], acc[3][jj]));
    #pragma unroll
    for (int jj = 0; jj < 4; ++jj) {
        m[jj] = fmaxf(m[jj], __shfl_xor(m[jj], 16, 64));
        m[jj] = fmaxf(m[jj], __shfl_xor(m[jj], 32, 64));
    }
    int lane = t & 63;
    if (lane < 16) {
        int p = p0 + (t >> 6);
        float4 bb = *(const float4*)&b2[lane * 4];
        float4 o4; o4.x = m[0] + bb.x; o4.y = m[1] + bb.y;
                   o4.z = m[2] + bb.z; o4.w = m[3] + bb.w;
        *(float4*)&out[(size_t)p * 64 + lane * 4] = o4;
    }
}

// ---------------- final MLP 192->128->64->32->2 + log_softmax ----------------
__global__ __launch_bounds__(256) void mlp_kernel(const float* __restrict__ x1,
                                                  const float* __restrict__ x2,
                                                  const float* __restrict__ x3,
                                                  const float* __restrict__ mw1, const float* __restrict__ mb1,
                                                  const float* __restrict__ mw2, const float* __restrict__ mb2,
                                                  const float* __restrict__ mw3, const float* __restrict__ mb3,
                                                  const float* __restrict__ mw4, const float* __restrict__ mb4,
                                                  float* __restrict__ out) {
    __shared__ float abuf[4][192 * 4];
    __shared__ float h1b[4][128 * 4];
    __shared__ float h2b[4][64 * 4];
    __shared__ float h3b[4][32 * 4];
    __shared__ float zb[4][4][2];
    int wave = threadIdx.x >> 6, lane = threadIdx.x & 63;
    int gw = blockIdx.x * 4 + wave;
    for (int g = gw; g < NPOINTS / 4; g += 4096) {
        int p0 = g * 4;
        #pragma unroll
        for (int q = 0; q < 4; ++q) {
            int p = p0 + q;
            abuf[wave][(lane) * 4 + q]       = x1[(size_t)p * 64 + lane];
            abuf[wave][(64 + lane) * 4 + q]  = x2[(size_t)p * 64 + lane];
            abuf[wave][(128 + lane) * 4 + q] = x3[(size_t)p * 64 + lane];
        }
        float a1c[2][4];
        #pragma unroll
        for (int h = 0; h < 2; ++h) {
            float bb = mb1[lane + 64 * h];
            #pragma unroll
            for (int q = 0; q < 4; ++q) a1c[h][q] = bb;
        }
        #pragma unroll 4
        for (int d = 0; d < 192; ++d) {
            const float4 a4 = *(const float4*)&abuf[wave][d * 4];
            float w0 = mw1[d * 128 + lane];
            float w1_ = mw1[d * 128 + 64 + lane];
            a1c[0][0] = fmaf(a4.x, w0, a1c[0][0]);
            a1c[0][1] = fmaf(a4.y, w0, a1c[0][1]);
            a1c[0][2] = fmaf(a4.z, w0, a1c[0][2]);
            a1c[0][3] = fmaf(a4.w, w0, a1c[0][3]);
            a1c[1][0] = fmaf(a4.x, w1_, a1c[1][0]);
            a1c[1][1] = fmaf(a4.y, w1_, a1c[1][1]);
            a1c[1][2] = fmaf(a4.z, w1_, a1c[1][2]);
            a1c[1][3] = fmaf(a4.w, w1_, a1c[1][3]);
        }
        #pragma unroll
        for (int h = 0; h < 2; ++h)
            #pragma unroll
            for (int q = 0; q < 4; ++q)
                h1b[wave][(lane + 64 * h) * 4 + q] = fmaxf(a1c[h][q], 0.f);
        float a2c[4];
        { float bb = mb2[lane];
          #pragma unroll
          for (int q = 0; q < 4; ++q) a2c[q] = bb; }
        #pragma unroll 4
        for (int d = 0; d < 128; ++d) {
            const float4 a4 = *(const float4*)&h1b[wave][d * 4];
            float w = mw2[d * 64 + lane];
            a2c[0] = fmaf(a4.x, w, a2c[0]);
            a2c[1] = fmaf(a4.y, w, a2c[1]);
            a2c[2] = fmaf(a4.z, w, a2c[2]);
            a2c[3] = fmaf(a4.w, w, a2c[3]);
        }
        #pragma unroll
        for (int q = 0; q < 4; ++q) h2b[wave][lane * 4 + q] = fmaxf(a2c[q], 0.f);
        int o3 = lane & 31;
        float a3c[4];
        { float bb = mb3[o3];
          #pragma unroll
          for (int q = 0; q < 4; ++q) a3c[q] = bb; }
        #pragma unroll 4
        for (int d = 0; d < 64; ++d) {
            const float4 a4 = *(const float4*)&h2b[wave][d * 4];
            float w = mw3[d * 32 + o3];
            a3c[0] = fmaf(a4.x, w, a3c[0]);
            a3c[1] = fmaf(a4.y, w, a3c[1]);
            a3c[2] = fmaf(a4.z, w, a3c[2]);
            a3c[3] = fmaf(a4.w, w, a3c[3]);
        }
        if (lane < 32) {
            #pragma unroll
            for (int q = 0; q < 4; ++q) h3b[wave][o3 * 4 + q] = fmaxf(a3c[q], 0.f);
        }
        int o4 = lane & 1;
        float a4c[4];
        { float bb = mb4[o4];
          #pragma unroll
          for (int q = 0; q < 4; ++q) a4c[q] = bb; }
        #pragma unroll
        for (int d = 0; d < 32; ++d) {
            const float4 a4 = *(const float4*)&h3b[wave][d * 4];
            float w = mw4[d * 2 + o4];
            a4c[0] = fmaf(a4.x, w, a4c[0]);
            a4c[1] = fmaf(a4.y, w, a4c[1]);
            a4c[2] = fmaf(a4.z, w, a4c[2]);
            a4c[3] = fmaf(a4.w, w, a4c[3]);
        }
        if (lane < 2) {
            #pragma unroll
            for (int q = 0; q < 4; ++q) zb[wave][q][lane] = a4c[q];
        }
        if (lane < 4) {
            int q = lane, p = p0 + q;
            float z0 = zb[wave][q][0], z1 = zb[wave][q][1];
            float m = fmaxf(z0, z1);
            float ls = m + logf(expf(z0 - m) + expf(z1 - m));
            out[(size_t)p * 2 + 0] = z0 - ls;
            out[(size_t)p * 2 + 1] = z1 - ls;
        }
    }
}

extern "C" void kernel_launch(void* const* d_in, const int* in_sizes, int n_in,
                              void* d_out, int out_size, void* d_ws, size_t ws_size,
                              hipStream_t stream) {
    const float* x0   = (const float*)d_in[0];
    const float* c1w1 = (const float*)d_in[1];  const float* c1b1 = (const float*)d_in[2];
    const float* c1w2 = (const float*)d_in[3];  const float* c1b2 = (const float*)d_in[4];
    const float* c2w1 = (const float*)d_in[5];  const float* c2b1 = (const float*)d_in[6];
    const float* c2w2 = (const float*)d_in[7];  const float* c2b2 = (const float*)d_in[8];
    const float* c3w1 = (const float*)d_in[9];  const float* c3b1 = (const float*)d_in[10];
    const float* c3w2 = (const float*)d_in[11]; const float* c3b2 = (const float*)d_in[12];
    const float* mw1  = (const float*)d_in[13]; const float* mb1  = (const float*)d_in[14];
    const float* mw2  = (const float*)d_in[15]; const float* mb2  = (const float*)d_in[16];
    const float* mw3  = (const float*)d_in[17]; const float* mb3  = (const float*)d_in[18];
    const float* mw4  = (const float*)d_in[19]; const float* mb4  = (const float*)d_in[20];

    float* ws = (float*)d_ws;
    const size_t NF = (size_t)NPOINTS * 64;
    float* x1 = ws;
    float* x2 = x1 + NF;
    float* x3 = x2 + NF;
    float* u  = x3 + NF;
    float* v  = u  + NF;
    float* sq = v  + NF;
    int*  idx = (int*)(sq + NPOINTS);
    ushort_t* xh = (ushort_t*)(idx + (size_t)NPOINTS * KNB);
    ushort_t* xl = xh + NF;
    float* cand_d = u;          // aliases: dead ranges don't overlap in time
    int*   cand_j = (int*)v;
    float* out = (float*)d_out;

    // ---- layer 1 (C_in = 1): fp32 knn ----
    sqnorm_kernel<1><<<NPOINTS / 64, 64, 0, stream>>>(x0, sq);
    knn_part1_kernel<<<(NPOINTS / 64) * NCHUNK1, 64, 0, stream>>>(x0, sq, cand_d, cand_j);
    knn_merge_kernel<NCHUNK1 * KNB><<<NPOINTS / 256, 256, 0, stream>>>(cand_d, cand_j, idx);
    uv1_kernel<<<1024, 256, 0, stream>>>(x0, c1w1, c1b1, u, v);
    edge_kernel<<<NPOINTS / 4, 256, 0, stream>>>(u, v, idx, c1w2, c1b2, x1);
    // ---- layer 2: MFMA knn ----
    sqnorm_kernel<64><<<NPOINTS / 64, 64, 0, stream>>>(x1, sq);
    split_kernel<<<NPOINTS / 64, 256, 0, stream>>>(x1, xh, xl);
    knn_mfma_kernel<<<NB * 16 * NCHUNK2, 64, 0, stream>>>(xh, xl, sq, cand_d, cand_j);
    knn_merge_kernel<NCHUNK2 * KNB><<<NPOINTS / 256, 256, 0, stream>>>(cand_d, cand_j, idx);
    uv_gemm_kernel<<<NPOINTS / 64, 256, 0, stream>>>(x1, c2w1, c2b1, u, v);
    edge_kernel<<<NPOINTS / 4, 256, 0, stream>>>(u, v, idx, c2w2, c2b2, x2);
    // ---- layer 3: MFMA knn ----
    sqnorm_kernel<64><<<NPOINTS / 64, 64, 0, stream>>>(x2, sq);
    split_kernel<<<NPOINTS / 64, 256, 0, stream>>>(x2, xh, xl);
    knn_mfma_kernel<<<NB * 16 * NCHUNK2, 64, 0, stream>>>(xh, xl, sq, cand_d, cand_j);
    knn_merge_kernel<NCHUNK2 * KNB><<<NPOINTS / 256, 256, 0, stream>>>(cand_d, cand_j, idx);
    uv_gemm_kernel<<<NPOINTS / 64, 256, 0, stream>>>(x2, c3w1, c3b1, u, v);
    edge_kernel<<<NPOINTS / 4, 256, 0, stream>>>(u, v, idx, c3w2, c3b2, x3);
    // ---- final MLP + log_softmax ----
    mlp_kernel<<<1024, 256, 0, stream>>>(x1, x2, x3, mw1, mb1, mw2, mb2,
                                         mw3, mb3, mw4, mb4, out);
}

// Round 5
// 886.579 us; speedup vs baseline: 4.7801x; 1.3275x over previous
//
#include <hip/hip_runtime.h>
#include <math.h>

typedef unsigned short ushort_t;
typedef unsigned int uint_t;
typedef __bf16 bf16x8_t __attribute__((ext_vector_type(8)));
typedef float f32x4_t __attribute__((ext_vector_type(4)));

static constexpr int NPTS = 1024;
static constexpr int NB = 64;
static constexpr int NPOINTS = NB * NPTS;   // 65536
static constexpr int KNB = 16;
static constexpr int NCHUNK1 = 4;           // layer-1 fp32 knn chunking
static constexpr int NCHUNK2 = 2;           // mfma knn chunking

__device__ __forceinline__ ushort_t f2bf(float f) {
    uint_t u = __float_as_uint(f);
    uint_t r = (u + 0x7FFFu + ((u >> 16) & 1u)) >> 16;
    return (ushort_t)r;
}
__device__ __forceinline__ float bf2f(ushort_t h) {
    return __uint_as_float(((uint_t)h) << 16);
}
// pack distance (clamped >=0, 22 bits kept) + batch-local j (10 bits).
// unsigned compare == (dist_q, j) lexicographic; only the neighbor SET matters
// downstream (max-pool over k), so 2^-13 relative quantization is benign.
__device__ __forceinline__ uint_t packdj(float d, int j) {
    return (__float_as_uint(fmaxf(d, 0.f)) & 0xFFFFFC00u) | (uint_t)j;
}
// branch-free sorted-16 insert: replace tail, then 15 unconditional min/max
// steps (sorted list is a fixed point for non-inserting lanes -> no exec mask).
__device__ __forceinline__ void insert16(uint_t* L, uint_t c) {
    L[15] = (c < L[15]) ? c : L[15];
    #pragma unroll
    for (int k = 15; k > 0; --k) {
        uint_t a = L[k - 1], b = L[k];
        L[k - 1] = a < b ? a : b;
        L[k]     = a < b ? b : a;
    }
}

// ---------------- squared norms ----------------
template<int C>
__global__ __launch_bounds__(64) void sqnorm_kernel(const float* __restrict__ x,
                                                    float* __restrict__ sq) {
    int p = blockIdx.x * 64 + threadIdx.x;
    const float* xp = x + (size_t)p * C;
    float s;
    if constexpr (C == 1) {
        s = xp[0] * xp[0];
    } else {
        float a0 = 0.f, a1 = 0.f, a2 = 0.f, a3 = 0.f;
        #pragma unroll
        for (int d = 0; d < C; d += 4) {
            a0 = fmaf(xp[d + 0], xp[d + 0], a0);
            a1 = fmaf(xp[d + 1], xp[d + 1], a1);
            a2 = fmaf(xp[d + 2], xp[d + 2], a2);
            a3 = fmaf(xp[d + 3], xp[d + 3], a3);
        }
        s = (a0 + a1) + (a2 + a3);
    }
    sq[p] = s;
}

// ---------------- fp32 -> bf16 hi/lo split (for MFMA knn) ----------------
__global__ __launch_bounds__(256) void split_kernel(const float* __restrict__ x,
                                                    ushort_t* __restrict__ xh,
                                                    ushort_t* __restrict__ xl) {
    int t = threadIdx.x;
    int p = blockIdx.x * 64 + (t >> 2);
    int c0 = (t & 3) * 16;
    const float* xp = x + (size_t)p * 64 + c0;
    ushort_t h[16], l[16];
    #pragma unroll
    for (int q = 0; q < 16; ++q) {
        float f = xp[q];
        ushort_t hs = f2bf(f);
        h[q] = hs;
        l[q] = f2bf(f - bf2f(hs));
    }
    ushort_t* oh = xh + (size_t)p * 64 + c0;
    ushort_t* ol = xl + (size_t)p * 64 + c0;
    #pragma unroll
    for (int q = 0; q < 2; ++q) {
        ((uint4*)oh)[q] = ((const uint4*)h)[q];
        ((uint4*)ol)[q] = ((const uint4*)l)[q];
    }
}

// ---------------- layer-1 knn (C=1): fp32 LDS-tile scan, packed top-16 ----------------
__global__ __launch_bounds__(64) void knn_part1_kernel(const float* __restrict__ pts,
                                                       const float* __restrict__ sq,
                                                       uint_t* __restrict__ cand) {
    constexpr int JT = 32;
    constexpr int JC = NPTS / NCHUNK1;           // 256
    __shared__ float tile[JT];
    __shared__ float tsq[JT];
    int chunk = blockIdx.x & (NCHUNK1 - 1);
    int pblk  = blockIdx.x >> 2;
    int i  = pblk * 64 + threadIdx.x;
    int b  = i >> 10;
    int il = i & 1023;
    const float* base = pts + (size_t)(b << 10);
    float xi = base[il];
    float sqi = sq[i];
    const float* sqb = sq + (b << 10);

    uint_t lst[KNB];
    #pragma unroll
    for (int k = 0; k < KNB; ++k) lst[k] = 0xFFFFFFFFu;

    int j0 = chunk * JC;
    for (int jt = 0; jt < JC; jt += JT) {
        if (threadIdx.x < JT) {
            tile[threadIdx.x] = base[j0 + jt + threadIdx.x];
            tsq[threadIdx.x] = sqb[j0 + jt + threadIdx.x];
        }
        __syncthreads();
        #pragma unroll 4
        for (int jj = 0; jj < JT; ++jj) {
            float dist = sqi + tsq[jj] - 2.0f * (xi * tile[jj]);
            insert16(lst, packdj(dist, j0 + jt + jj));
        }
        __syncthreads();
    }
    #pragma unroll
    for (int k = 0; k < KNB; ++k)
        cand[(size_t)(chunk * KNB + k) * NPOINTS + i] = lst[k];
}

// ---------------- MFMA knn (C=64): 16x16x32 bf16 hi/lo, packed 4-sublist top-16 ----
// 1 wave = 64 i x 512 j. Per 16-j group: 24 MFMAs -> packed dist tile in LDS ->
// lane=i inserts 16 j's round-robin into 4 register sublists (dep-chain ILP).
__global__ __launch_bounds__(64, 2) void knn_mfma_kernel(const ushort_t* __restrict__ xh,
                                                         const ushort_t* __restrict__ xl,
                                                         const float* __restrict__ sq,
                                                         uint_t* __restrict__ cand) {
    constexpr int JC = NPTS / NCHUNK2;           // 512
    __shared__ uint_t dbuf[16 * 68];
    __shared__ float sqs[JC];
    int chunk = blockIdx.x & (NCHUNK2 - 1);
    int ib    = (blockIdx.x >> 1) & 15;
    int b     = blockIdx.x >> 5;
    int i0    = b * NPTS + ib * 64;
    int lane  = threadIdx.x;
    int m = lane & 15, quad = lane >> 4;
    int j0c = chunk * JC;

    for (int t = lane; t < JC; t += 64) sqs[t] = sq[b * NPTS + j0c + t];

    bf16x8_t Ah[4][2], Al[4][2];
    #pragma unroll
    for (int it = 0; it < 4; ++it) {
        #pragma unroll
        for (int kh = 0; kh < 2; ++kh) {
            size_t off = ((size_t)(i0 + it * 16 + m)) * 64 + kh * 32 + quad * 8;
            Ah[it][kh] = *(const bf16x8_t*)(xh + off);
            Al[it][kh] = *(const bf16x8_t*)(xl + off);
        }
    }
    float4 sqi[4];
    #pragma unroll
    for (int it = 0; it < 4; ++it)
        sqi[it] = *(const float4*)&sq[i0 + it * 16 + quad * 4];

    uint_t lst[4][KNB];
    #pragma unroll
    for (int s = 0; s < 4; ++s)
        #pragma unroll
        for (int k = 0; k < KNB; ++k) lst[s][k] = 0xFFFFFFFFu;
    __syncthreads();

    for (int g = 0; g < JC / 16; ++g) {
        int jg = j0c + g * 16;                       // batch-local j base
        size_t boff = ((size_t)(b * NPTS + jg + m)) * 64 + quad * 8;
        bf16x8_t Bh0 = *(const bf16x8_t*)(xh + boff);
        bf16x8_t Bh1 = *(const bf16x8_t*)(xh + boff + 32);
        bf16x8_t Bl0 = *(const bf16x8_t*)(xl + boff);
        bf16x8_t Bl1 = *(const bf16x8_t*)(xl + boff + 32);
        float sqj = sqs[g * 16 + m];
        int jm = jg + m;
        #pragma unroll
        for (int it = 0; it < 4; ++it) {
            f32x4_t acc = {0.f, 0.f, 0.f, 0.f};
            acc = __builtin_amdgcn_mfma_f32_16x16x32_bf16(Ah[it][0], Bh0, acc, 0, 0, 0);
            acc = __builtin_amdgcn_mfma_f32_16x16x32_bf16(Ah[it][1], Bh1, acc, 0, 0, 0);
            acc = __builtin_amdgcn_mfma_f32_16x16x32_bf16(Ah[it][0], Bl0, acc, 0, 0, 0);
            acc = __builtin_amdgcn_mfma_f32_16x16x32_bf16(Ah[it][1], Bl1, acc, 0, 0, 0);
            acc = __builtin_amdgcn_mfma_f32_16x16x32_bf16(Al[it][0], Bh0, acc, 0, 0, 0);
            acc = __builtin_amdgcn_mfma_f32_16x16x32_bf16(Al[it][1], Bh1, acc, 0, 0, 0);
            uint4 pv;
            pv.x = packdj(sqi[it].x + sqj - 2.0f * acc[0], jm);
            pv.y = packdj(sqi[it].y + sqj - 2.0f * acc[1], jm);
            pv.z = packdj(sqi[it].z + sqj - 2.0f * acc[2], jm);
            pv.w = packdj(sqi[it].w + sqj - 2.0f * acc[3], jm);
            // dist(i_local = it*16 + quad*4 + r, j_local = m)
            *(uint4*)&dbuf[m * 68 + it * 16 + quad * 4] = pv;
        }
        __syncthreads();
        #pragma unroll
        for (int jj = 0; jj < 16; ++jj)
            insert16(lst[jj & 3], dbuf[jj * 68 + lane]);
        __syncthreads();
    }
    #pragma unroll
    for (int s = 0; s < 4; ++s)
        #pragma unroll
        for (int k = 0; k < KNB; ++k)
            cand[(size_t)(chunk * 64 + s * 16 + k) * NPOINTS + i0 + lane] = lst[s][k];
}

// ---------------- knn merge: NC packed candidates -> final top-16 indices ----------------
template<int NC>
__global__ __launch_bounds__(256) void knn_merge_kernel(const uint_t* __restrict__ cand,
                                                        int* __restrict__ idx_out) {
    int i = blockIdx.x * 256 + threadIdx.x;
    uint_t lst[KNB];
    #pragma unroll
    for (int k = 0; k < KNB; ++k) lst[k] = 0xFFFFFFFFu;
    #pragma unroll 4
    for (int t = 0; t < NC; ++t)
        insert16(lst, cand[(size_t)t * NPOINTS + i]);
    int* op = idx_out + (size_t)i * KNB;
    #pragma unroll
    for (int k = 0; k < KNB; ++k) op[k] = (int)(lst[k] & 0x3FFu);
}

// ---------------- uv for layer 1 (C_in = 1): elementwise ----------------
__global__ __launch_bounds__(256) void uv1_kernel(const float* __restrict__ x,
                                                  const float* __restrict__ w1,
                                                  const float* __restrict__ b1,
                                                  float* __restrict__ u,
                                                  float* __restrict__ v) {
    int lane = threadIdx.x & 63, wave = threadIdx.x >> 6;
    float wa = w1[lane], wb = w1[64 + lane], bb = b1[lane];
    float wd = wa - wb;
    int gw = blockIdx.x * 4 + wave;
    for (int p = gw; p < NPOINTS; p += 4096) {
        float xv = x[p];
        u[(size_t)p * 64 + lane] = fmaf(xv, wd, bb);
        v[(size_t)p * 64 + lane] = xv * wb;
    }
}

// ---------------- uv GEMM (CIN=64) ----------------
__global__ __launch_bounds__(256) void uv_gemm_kernel(const float* __restrict__ x,
                                                      const float* __restrict__ w1,
                                                      const float* __restrict__ b1,
                                                      float* __restrict__ u,
                                                      float* __restrict__ v) {
    __shared__ float As[64 * 68];
    __shared__ float Bs[64 * 128];
    int t = threadIdx.x;
    int p0 = blockIdx.x * 64;
    for (int g = t; g < 64 * 16; g += 256) {
        int c = g >> 4, o4 = (g & 15) * 4;
        float4 wa = *(const float4*)&w1[c * 64 + o4];
        float4 wb = *(const float4*)&w1[(64 + c) * 64 + o4];
        float4 d; d.x = wa.x - wb.x; d.y = wa.y - wb.y; d.z = wa.z - wb.z; d.w = wa.w - wb.w;
        *(float4*)&Bs[c * 128 + o4] = d;
    }
    for (int g = t; g < 64 * 16; g += 256) {
        int c = g >> 4, o4 = (g & 15) * 4;
        *(float4*)&Bs[c * 128 + 64 + o4] = *(const float4*)&w1[(64 + c) * 64 + o4];
    }
    {
        int pq = t >> 4, cq = t & 15;
        const float* xp = x + (size_t)(p0 + pq * 4) * 64 + cq * 4;
        float4 r0 = *(const float4*)&xp[0 * 64];
        float4 r1 = *(const float4*)&xp[1 * 64];
        float4 r2 = *(const float4*)&xp[2 * 64];
        float4 r3 = *(const float4*)&xp[3 * 64];
        float4 c0; c0.x = r0.x; c0.y = r1.x; c0.z = r2.x; c0.w = r3.x;
        float4 c1; c1.x = r0.y; c1.y = r1.y; c1.z = r2.y; c1.w = r3.y;
        float4 c2; c2.x = r0.z; c2.y = r1.z; c2.z = r2.z; c2.w = r3.z;
        float4 c3; c3.x = r0.w; c3.y = r1.w; c3.z = r2.w; c3.w = r3.w;
        *(float4*)&As[(cq * 4 + 0) * 68 + pq * 4] = c0;
        *(float4*)&As[(cq * 4 + 1) * 68 + pq * 4] = c1;
        *(float4*)&As[(cq * 4 + 2) * 68 + pq * 4] = c2;
        *(float4*)&As[(cq * 4 + 3) * 68 + pq * 4] = c3;
    }
    __syncthreads();
    int rg = t >> 4;
    int cg = t & 15;
    float acc[4][8];
    #pragma unroll
    for (int i = 0; i < 4; ++i)
        #pragma unroll
        for (int jj = 0; jj < 8; ++jj) acc[i][jj] = 0.f;
    #pragma unroll 4
    for (int c = 0; c < 64; ++c) {
        float4 a4 = *(const float4*)&As[c * 68 + rg * 4];
        float4 b0 = *(const float4*)&Bs[c * 128 + cg * 8];
        float4 b4 = *(const float4*)&Bs[c * 128 + cg * 8 + 4];
        float av[4] = {a4.x, a4.y, a4.z, a4.w};
        float bv[8] = {b0.x, b0.y, b0.z, b0.w, b4.x, b4.y, b4.z, b4.w};
        #pragma unroll
        for (int i = 0; i < 4; ++i)
            #pragma unroll
            for (int jj = 0; jj < 8; ++jj)
                acc[i][jj] = fmaf(av[i], bv[jj], acc[i][jj]);
    }
    if (cg < 8) {
        float4 bb0 = *(const float4*)&b1[cg * 8];
        float4 bb1 = *(const float4*)&b1[cg * 8 + 4];
        #pragma unroll
        for (int i = 0; i < 4; ++i) {
            size_t p = p0 + rg * 4 + i;
            float4 o0; o0.x = acc[i][0] + bb0.x; o0.y = acc[i][1] + bb0.y;
                       o0.z = acc[i][2] + bb0.z; o0.w = acc[i][3] + bb0.w;
            float4 o1; o1.x = acc[i][4] + bb1.x; o1.y = acc[i][5] + bb1.y;
                       o1.z = acc[i][6] + bb1.z; o1.w = acc[i][7] + bb1.w;
            *(float4*)&u[p * 64 + cg * 8]     = o0;
            *(float4*)&u[p * 64 + cg * 8 + 4] = o1;
        }
    } else {
        int o = (cg - 8) * 8;
        #pragma unroll
        for (int i = 0; i < 4; ++i) {
            size_t p = p0 + rg * 4 + i;
            float4 o0; o0.x = acc[i][0]; o0.y = acc[i][1]; o0.z = acc[i][2]; o0.w = acc[i][3];
            float4 o1; o1.x = acc[i][4]; o1.y = acc[i][5]; o1.z = acc[i][6]; o1.w = acc[i][7];
            *(float4*)&v[p * 64 + o]     = o0;
            *(float4*)&v[p * 64 + o + 4] = o1;
        }
    }
}

// ---------------- edge GEMM ----------------
__global__ __launch_bounds__(256) void edge_kernel(const float* __restrict__ u,
                                                   const float* __restrict__ v,
                                                   const int* __restrict__ idx,
                                                   const float* __restrict__ w2,
                                                   const float* __restrict__ b2,
                                                   float* __restrict__ out) {
    __shared__ float As[64 * 64];
    __shared__ float Bs[64 * 64];
    int t = threadIdx.x;
    int p0 = blockIdx.x * 4;
    #pragma unroll
    for (int g = t; g < 64 * 16; g += 256)
        *(float4*)&Bs[g * 4] = *(const float4*)&w2[g * 4];
    {
        int r = t & 63, cq = t >> 6;
        int pl = r >> 4, k = r & 15;
        int p = p0 + pl;
        int b = p >> 10;
        int j = idx[p * 16 + k];
        const float* up = u + (size_t)p * 64 + cq * 16;
        const float* vp = v + ((size_t)(b << 10) + j) * 64 + cq * 16;
        #pragma unroll
        for (int q = 0; q < 4; ++q) {
            float4 uq = *(const float4*)&up[q * 4];
            float4 vq = *(const float4*)&vp[q * 4];
            int c = cq * 16 + q * 4;
            As[(c + 0) * 64 + r] = fmaxf(uq.x + vq.x, 0.f);
            As[(c + 1) * 64 + r] = fmaxf(uq.y + vq.y, 0.f);
            As[(c + 2) * 64 + r] = fmaxf(uq.z + vq.z, 0.f);
            As[(c + 3) * 64 + r] = fmaxf(uq.w + vq.w, 0.f);
        }
    }
    __syncthreads();
    int r4 = t >> 4;
    int c4 = t & 15;
    float acc[4][4];
    #pragma unroll
    for (int i = 0; i < 4; ++i)
        #pragma unroll
        for (int jj = 0; jj < 4; ++jj) acc[i][jj] = 0.f;
    #pragma unroll 4
    for (int c = 0; c < 64; ++c) {
        float4 a4 = *(const float4*)&As[c * 64 + r4 * 4];
        float4 b4 = *(const float4*)&Bs[c * 64 + c4 * 4];
        float av[4] = {a4.x, a4.y, a4.z, a4.w};
        float bv[4] = {b4.x, b4.y, b4.z, b4.w};
        #pragma unroll
        for (int i = 0; i < 4; ++i)
            #pragma unroll
            for (int jj = 0; jj < 4; ++jj)
                acc[i][jj] = fmaf(av[i], bv[jj], acc[i][jj]);
    }
    float m[4];
    #pragma unroll
    for (int jj = 0; jj < 4; ++jj)
        m[jj] = fmaxf(fmaxf(acc[0][jj], acc[1][jj]), fmaxf(acc[2][jj], acc[3][jj]));
    #pragma unroll
    for (int jj = 0; jj < 4; ++jj) {
        m[jj] = fmaxf(m[jj], __shfl_xor(m[jj], 16, 64));
        m[jj] = fmaxf(m[jj], __shfl_xor(m[jj], 32, 64));
    }
    int lane = t & 63;
    if (lane < 16) {
        int p = p0 + (t >> 6);
        float4 bb = *(const float4*)&b2[lane * 4];
        float4 o4; o4.x = m[0] + bb.x; o4.y = m[1] + bb.y;
                   o4.z = m[2] + bb.z; o4.w = m[3] + bb.w;
        *(float4*)&out[(size_t)p * 64 + lane * 4] = o4;
    }
}

// ---------------- final MLP 192->128->64->32->2 + log_softmax ----------------
__global__ __launch_bounds__(256) void mlp_kernel(const float* __restrict__ x1,
                                                  const float* __restrict__ x2,
                                                  const float* __restrict__ x3,
                                                  const float* __restrict__ mw1, const float* __restrict__ mb1,
                                                  const float* __restrict__ mw2, const float* __restrict__ mb2,
                                                  const float* __restrict__ mw3, const float* __restrict__ mb3,
                                                  const float* __restrict__ mw4, const float* __restrict__ mb4,
                                                  float* __restrict__ out) {
    __shared__ float abuf[4][192 * 4];
    __shared__ float h1b[4][128 * 4];
    __shared__ float h2b[4][64 * 4];
    __shared__ float h3b[4][32 * 4];
    __shared__ float zb[4][4][2];
    int wave = threadIdx.x >> 6, lane = threadIdx.x & 63;
    int gw = blockIdx.x * 4 + wave;
    for (int g = gw; g < NPOINTS / 4; g += 4096) {
        int p0 = g * 4;
        #pragma unroll
        for (int q = 0; q < 4; ++q) {
            int p = p0 + q;
            abuf[wave][(lane) * 4 + q]       = x1[(size_t)p * 64 + lane];
            abuf[wave][(64 + lane) * 4 + q]  = x2[(size_t)p * 64 + lane];
            abuf[wave][(128 + lane) * 4 + q] = x3[(size_t)p * 64 + lane];
        }
        float a1c[2][4];
        #pragma unroll
        for (int h = 0; h < 2; ++h) {
            float bb = mb1[lane + 64 * h];
            #pragma unroll
            for (int q = 0; q < 4; ++q) a1c[h][q] = bb;
        }
        #pragma unroll 4
        for (int d = 0; d < 192; ++d) {
            const float4 a4 = *(const float4*)&abuf[wave][d * 4];
            float w0 = mw1[d * 128 + lane];
            float w1_ = mw1[d * 128 + 64 + lane];
            a1c[0][0] = fmaf(a4.x, w0, a1c[0][0]);
            a1c[0][1] = fmaf(a4.y, w0, a1c[0][1]);
            a1c[0][2] = fmaf(a4.z, w0, a1c[0][2]);
            a1c[0][3] = fmaf(a4.w, w0, a1c[0][3]);
            a1c[1][0] = fmaf(a4.x, w1_, a1c[1][0]);
            a1c[1][1] = fmaf(a4.y, w1_, a1c[1][1]);
            a1c[1][2] = fmaf(a4.z, w1_, a1c[1][2]);
            a1c[1][3] = fmaf(a4.w, w1_, a1c[1][3]);
        }
        #pragma unroll
        for (int h = 0; h < 2; ++h)
            #pragma unroll
            for (int q = 0; q < 4; ++q)
                h1b[wave][(lane + 64 * h) * 4 + q] = fmaxf(a1c[h][q], 0.f);
        float a2c[4];
        { float bb = mb2[lane];
          #pragma unroll
          for (int q = 0; q < 4; ++q) a2c[q] = bb; }
        #pragma unroll 4
        for (int d = 0; d < 128; ++d) {
            const float4 a4 = *(const float4*)&h1b[wave][d * 4];
            float w = mw2[d * 64 + lane];
            a2c[0] = fmaf(a4.x, w, a2c[0]);
            a2c[1] = fmaf(a4.y, w, a2c[1]);
            a2c[2] = fmaf(a4.z, w, a2c[2]);
            a2c[3] = fmaf(a4.w, w, a2c[3]);
        }
        #pragma unroll
        for (int q = 0; q < 4; ++q) h2b[wave][lane * 4 + q] = fmaxf(a2c[q], 0.f);
        int o3 = lane & 31;
        float a3c[4];
        { float bb = mb3[o3];
          #pragma unroll
          for (int q = 0; q < 4; ++q) a3c[q] = bb; }
        #pragma unroll 4
        for (int d = 0; d < 64; ++d) {
            const float4 a4 = *(const float4*)&h2b[wave][d * 4];
            float w = mw3[d * 32 + o3];
            a3c[0] = fmaf(a4.x, w, a3c[0]);
            a3c[1] = fmaf(a4.y, w, a3c[1]);
            a3c[2] = fmaf(a4.z, w, a3c[2]);
            a3c[3] = fmaf(a4.w, w, a3c[3]);
        }
        if (lane < 32) {
            #pragma unroll
            for (int q = 0; q < 4; ++q) h3b[wave][o3 * 4 + q] = fmaxf(a3c[q], 0.f);
        }
        int o4 = lane & 1;
        float a4c[4];
        { float bb = mb4[o4];
          #pragma unroll
          for (int q = 0; q < 4; ++q) a4c[q] = bb; }
        #pragma unroll
        for (int d = 0; d < 32; ++d) {
            const float4 a4 = *(const float4*)&h3b[wave][d * 4];
            float w = mw4[d * 2 + o4];
            a4c[0] = fmaf(a4.x, w, a4c[0]);
            a4c[1] = fmaf(a4.y, w, a4c[1]);
            a4c[2] = fmaf(a4.z, w, a4c[2]);
            a4c[3] = fmaf(a4.w, w, a4c[3]);
        }
        if (lane < 2) {
            #pragma unroll
            for (int q = 0; q < 4; ++q) zb[wave][q][lane] = a4c[q];
        }
        if (lane < 4) {
            int q = lane, p = p0 + q;
            float z0 = zb[wave][q][0], z1 = zb[wave][q][1];
            float m = fmaxf(z0, z1);
            float ls = m + logf(expf(z0 - m) + expf(z1 - m));
            out[(size_t)p * 2 + 0] = z0 - ls;
            out[(size_t)p * 2 + 1] = z1 - ls;
        }
    }
}

extern "C" void kernel_launch(void* const* d_in, const int* in_sizes, int n_in,
                              void* d_out, int out_size, void* d_ws, size_t ws_size,
                              hipStream_t stream) {
    const float* x0   = (const float*)d_in[0];
    const float* c1w1 = (const float*)d_in[1];  const float* c1b1 = (const float*)d_in[2];
    const float* c1w2 = (const float*)d_in[3];  const float* c1b2 = (const float*)d_in[4];
    const float* c2w1 = (const float*)d_in[5];  const float* c2b1 = (const float*)d_in[6];
    const float* c2w2 = (const float*)d_in[7];  const float* c2b2 = (const float*)d_in[8];
    const float* c3w1 = (const float*)d_in[9];  const float* c3b1 = (const float*)d_in[10];
    const float* c3w2 = (const float*)d_in[11]; const float* c3b2 = (const float*)d_in[12];
    const float* mw1  = (const float*)d_in[13]; const float* mb1  = (const float*)d_in[14];
    const float* mw2  = (const float*)d_in[15]; const float* mb2  = (const float*)d_in[16];
    const float* mw3  = (const float*)d_in[17]; const float* mb3  = (const float*)d_in[18];
    const float* mw4  = (const float*)d_in[19]; const float* mb4  = (const float*)d_in[20];

    float* ws = (float*)d_ws;
    const size_t NF = (size_t)NPOINTS * 64;
    float* x1 = ws;
    float* x2 = x1 + NF;
    float* x3 = x2 + NF;
    float* u  = x3 + NF;
    float* v  = u  + NF;
    float* sq = v  + NF;
    int*  idx = (int*)(sq + NPOINTS);
    ushort_t* xh = (ushort_t*)(idx + (size_t)NPOINTS * KNB);
    ushort_t* xl = xh + NF;
    // packed candidates span u..v (2*NF uints = 128 slots * NPOINTS max);
    // dead ranges don't overlap in time (stream-ordered).
    uint_t* cand = (uint_t*)u;
    float* out = (float*)d_out;

    // ---- layer 1 (C_in = 1): fp32 knn ----
    sqnorm_kernel<1><<<NPOINTS / 64, 64, 0, stream>>>(x0, sq);
    knn_part1_kernel<<<(NPOINTS / 64) * NCHUNK1, 64, 0, stream>>>(x0, sq, cand);
    knn_merge_kernel<NCHUNK1 * KNB><<<NPOINTS / 256, 256, 0, stream>>>(cand, idx);
    uv1_kernel<<<1024, 256, 0, stream>>>(x0, c1w1, c1b1, u, v);
    edge_kernel<<<NPOINTS / 4, 256, 0, stream>>>(u, v, idx, c1w2, c1b2, x1);
    // ---- layer 2: MFMA knn ----
    sqnorm_kernel<64><<<NPOINTS / 64, 64, 0, stream>>>(x1, sq);
    split_kernel<<<NPOINTS / 64, 256, 0, stream>>>(x1, xh, xl);
    knn_mfma_kernel<<<NB * 16 * NCHUNK2, 64, 0, stream>>>(xh, xl, sq, cand);
    knn_merge_kernel<NCHUNK2 * 64><<<NPOINTS / 256, 256, 0, stream>>>(cand, idx);
    uv_gemm_kernel<<<NPOINTS / 64, 256, 0, stream>>>(x1, c2w1, c2b1, u, v);
    edge_kernel<<<NPOINTS / 4, 256, 0, stream>>>(u, v, idx, c2w2, c2b2, x2);
    // ---- layer 3: MFMA knn ----
    sqnorm_kernel<64><<<NPOINTS / 64, 64, 0, stream>>>(x2, sq);
    split_kernel<<<NPOINTS / 64, 256, 0, stream>>>(x2, xh, xl);
    knn_mfma_kernel<<<NB * 16 * NCHUNK2, 64, 0, stream>>>(xh, xl, sq, cand);
    knn_merge_kernel<NCHUNK2 * 64><<<NPOINTS / 256, 256, 0, stream>>>(cand, idx);
    uv_gemm_kernel<<<NPOINTS / 64, 256, 0, stream>>>(x2, c3w1, c3b1, u, v);
    edge_kernel<<<NPOINTS / 4, 256, 0, stream>>>(u, v, idx, c3w2, c3b2, x3);
    // ---- final MLP + log_softmax ----
    mlp_kernel<<<1024, 256, 0, stream>>>(x1, x2, x3, mw1, mb1, mw2, mb2,
                                         mw3, mb3, mw4, mb4, out);
}

// Round 6
// 804.636 us; speedup vs baseline: 5.2669x; 1.1018x over previous
//
#include <hip/hip_runtime.h>
#include <math.h>

typedef unsigned short ushort_t;
typedef unsigned int uint_t;
typedef __bf16 bf16x8_t __attribute__((ext_vector_type(8)));
typedef float f32x4_t __attribute__((ext_vector_type(4)));

static constexpr int NPTS = 1024;
static constexpr int NB = 64;
static constexpr int NPOINTS = NB * NPTS;   // 65536
static constexpr int KNB = 16;
static constexpr int NCHUNK1 = 4;           // layer-1 fp32 knn chunking
static constexpr int NCHUNK2 = 2;           // mfma knn chunking

__device__ __forceinline__ ushort_t f2bf(float f) {
    uint_t u = __float_as_uint(f);
    uint_t r = (u + 0x7FFFu + ((u >> 16) & 1u)) >> 16;
    return (ushort_t)r;
}
__device__ __forceinline__ float bf2f(ushort_t h) {
    return __uint_as_float(((uint_t)h) << 16);
}
// pack distance (clamped >=0, 22 bits kept) + batch-local j (10 bits).
__device__ __forceinline__ uint_t packdj(float d, int j) {
    return (__float_as_uint(fmaxf(d, 0.f)) & 0xFFFFFC00u) | (uint_t)j;
}
// branch-free sorted-16 insert (min/max network, exec-uniform).
__device__ __forceinline__ void insert16(uint_t* L, uint_t c) {
    L[15] = (c < L[15]) ? c : L[15];
    #pragma unroll
    for (int k = 15; k > 0; --k) {
        uint_t a = L[k - 1], b = L[k];
        L[k - 1] = a < b ? a : b;
        L[k]     = a < b ? b : a;
    }
}

// ---------------- squared norms ----------------
template<int C>
__global__ __launch_bounds__(64) void sqnorm_kernel(const float* __restrict__ x,
                                                    float* __restrict__ sq) {
    int p = blockIdx.x * 64 + threadIdx.x;
    const float* xp = x + (size_t)p * C;
    float s;
    if constexpr (C == 1) {
        s = xp[0] * xp[0];
    } else {
        float a0 = 0.f, a1 = 0.f, a2 = 0.f, a3 = 0.f;
        #pragma unroll
        for (int d = 0; d < C; d += 4) {
            a0 = fmaf(xp[d + 0], xp[d + 0], a0);
            a1 = fmaf(xp[d + 1], xp[d + 1], a1);
            a2 = fmaf(xp[d + 2], xp[d + 2], a2);
            a3 = fmaf(xp[d + 3], xp[d + 3], a3);
        }
        s = (a0 + a1) + (a2 + a3);
    }
    sq[p] = s;
}

// ---------------- layer-1 knn (C=1): fp32 LDS-tile scan, packed top-16 ----------------
__global__ __launch_bounds__(64) void knn_part1_kernel(const float* __restrict__ pts,
                                                       const float* __restrict__ sq,
                                                       uint_t* __restrict__ cand) {
    constexpr int JT = 32;
    constexpr int JC = NPTS / NCHUNK1;           // 256
    __shared__ float tile[JT];
    __shared__ float tsq[JT];
    int chunk = blockIdx.x & (NCHUNK1 - 1);
    int pblk  = blockIdx.x >> 2;
    int i  = pblk * 64 + threadIdx.x;
    int b  = i >> 10;
    int il = i & 1023;
    const float* base = pts + (size_t)(b << 10);
    float xi = base[il];
    float sqi = sq[i];
    const float* sqb = sq + (b << 10);

    uint_t lst[KNB];
    #pragma unroll
    for (int k = 0; k < KNB; ++k) lst[k] = 0xFFFFFFFFu;

    int j0 = chunk * JC;
    for (int jt = 0; jt < JC; jt += JT) {
        if (threadIdx.x < JT) {
            tile[threadIdx.x] = base[j0 + jt + threadIdx.x];
            tsq[threadIdx.x] = sqb[j0 + jt + threadIdx.x];
        }
        __syncthreads();
        #pragma unroll 4
        for (int jj = 0; jj < JT; ++jj) {
            float dist = sqi + tsq[jj] - 2.0f * (xi * tile[jj]);
            insert16(lst, packdj(dist, j0 + jt + jj));
        }
        __syncthreads();
    }
    #pragma unroll
    for (int k = 0; k < KNB; ++k)
        cand[(size_t)(chunk * KNB + k) * NPOINTS + i] = lst[k];
}

// ---------------- MFMA knn (C=64): 16x16x32 bf16 hi/lo, packed 4-sublist top-16 ----
__global__ __launch_bounds__(64, 2) void knn_mfma_kernel(const ushort_t* __restrict__ xh,
                                                         const ushort_t* __restrict__ xl,
                                                         const float* __restrict__ sq,
                                                         uint_t* __restrict__ cand) {
    constexpr int JC = NPTS / NCHUNK2;           // 512
    __shared__ uint_t dbuf[16 * 68];
    __shared__ float sqs[JC];
    int chunk = blockIdx.x & (NCHUNK2 - 1);
    int ib    = (blockIdx.x >> 1) & 15;
    int b     = blockIdx.x >> 5;
    int i0    = b * NPTS + ib * 64;
    int lane  = threadIdx.x;
    int m = lane & 15, quad = lane >> 4;
    int j0c = chunk * JC;

    for (int t = lane; t < JC; t += 64) sqs[t] = sq[b * NPTS + j0c + t];

    bf16x8_t Ah[4][2], Al[4][2];
    #pragma unroll
    for (int it = 0; it < 4; ++it) {
        #pragma unroll
        for (int kh = 0; kh < 2; ++kh) {
            size_t off = ((size_t)(i0 + it * 16 + m)) * 64 + kh * 32 + quad * 8;
            Ah[it][kh] = *(const bf16x8_t*)(xh + off);
            Al[it][kh] = *(const bf16x8_t*)(xl + off);
        }
    }
    float4 sqi[4];
    #pragma unroll
    for (int it = 0; it < 4; ++it)
        sqi[it] = *(const float4*)&sq[i0 + it * 16 + quad * 4];

    uint_t lst[4][KNB];
    #pragma unroll
    for (int s = 0; s < 4; ++s)
        #pragma unroll
        for (int k = 0; k < KNB; ++k) lst[s][k] = 0xFFFFFFFFu;
    __syncthreads();

    for (int g = 0; g < JC / 16; ++g) {
        int jg = j0c + g * 16;                       // batch-local j base
        size_t boff = ((size_t)(b * NPTS + jg + m)) * 64 + quad * 8;
        bf16x8_t Bh0 = *(const bf16x8_t*)(xh + boff);
        bf16x8_t Bh1 = *(const bf16x8_t*)(xh + boff + 32);
        bf16x8_t Bl0 = *(const bf16x8_t*)(xl + boff);
        bf16x8_t Bl1 = *(const bf16x8_t*)(xl + boff + 32);
        float sqj = sqs[g * 16 + m];
        int jm = jg + m;
        #pragma unroll
        for (int it = 0; it < 4; ++it) {
            f32x4_t acc = {0.f, 0.f, 0.f, 0.f};
            acc = __builtin_amdgcn_mfma_f32_16x16x32_bf16(Ah[it][0], Bh0, acc, 0, 0, 0);
            acc = __builtin_amdgcn_mfma_f32_16x16x32_bf16(Ah[it][1], Bh1, acc, 0, 0, 0);
            acc = __builtin_amdgcn_mfma_f32_16x16x32_bf16(Ah[it][0], Bl0, acc, 0, 0, 0);
            acc = __builtin_amdgcn_mfma_f32_16x16x32_bf16(Ah[it][1], Bl1, acc, 0, 0, 0);
            acc = __builtin_amdgcn_mfma_f32_16x16x32_bf16(Al[it][0], Bh0, acc, 0, 0, 0);
            acc = __builtin_amdgcn_mfma_f32_16x16x32_bf16(Al[it][1], Bh1, acc, 0, 0, 0);
            uint4 pv;
            pv.x = packdj(sqi[it].x + sqj - 2.0f * acc[0], jm);
            pv.y = packdj(sqi[it].y + sqj - 2.0f * acc[1], jm);
            pv.z = packdj(sqi[it].z + sqj - 2.0f * acc[2], jm);
            pv.w = packdj(sqi[it].w + sqj - 2.0f * acc[3], jm);
            *(uint4*)&dbuf[m * 68 + it * 16 + quad * 4] = pv;
        }
        __syncthreads();
        #pragma unroll
        for (int jj = 0; jj < 16; ++jj)
            insert16(lst[jj & 3], dbuf[jj * 68 + lane]);
        __syncthreads();
    }
    #pragma unroll
    for (int s = 0; s < 4; ++s)
        #pragma unroll
        for (int k = 0; k < KNB; ++k)
            cand[(size_t)(chunk * 64 + s * 16 + k) * NPOINTS + i0 + lane] = lst[s][k];
}

// ---------------- knn merge: NC packed candidates -> final top-16 indices ----------------
template<int NC>
__global__ __launch_bounds__(256) void knn_merge_kernel(const uint_t* __restrict__ cand,
                                                        int* __restrict__ idx_out) {
    int i = blockIdx.x * 256 + threadIdx.x;
    uint_t lst[KNB];
    #pragma unroll
    for (int k = 0; k < KNB; ++k) lst[k] = 0xFFFFFFFFu;
    #pragma unroll 4
    for (int t = 0; t < NC; ++t)
        insert16(lst, cand[(size_t)t * NPOINTS + i]);
    int* op = idx_out + (size_t)i * KNB;
    #pragma unroll
    for (int k = 0; k < KNB; ++k) op[k] = (int)(lst[k] & 0x3FFu);
}

// ---------------- uv for layer 1 (C_in = 1): elementwise ----------------
__global__ __launch_bounds__(256) void uv1_kernel(const float* __restrict__ x,
                                                  const float* __restrict__ w1,
                                                  const float* __restrict__ b1,
                                                  float* __restrict__ u,
                                                  float* __restrict__ v) {
    int lane = threadIdx.x & 63, wave = threadIdx.x >> 6;
    float wa = w1[lane], wb = w1[64 + lane], bb = b1[lane];
    float wd = wa - wb;
    int gw = blockIdx.x * 4 + wave;
    for (int p = gw; p < NPOINTS; p += 4096) {
        float xv = x[p];
        u[(size_t)p * 64 + lane] = fmaf(xv, wd, bb);
        v[(size_t)p * 64 + lane] = xv * wb;
    }
}

// ---------------- uv GEMM (CIN=64) ----------------
__global__ __launch_bounds__(256) void uv_gemm_kernel(const float* __restrict__ x,
                                                      const float* __restrict__ w1,
                                                      const float* __restrict__ b1,
                                                      float* __restrict__ u,
                                                      float* __restrict__ v) {
    __shared__ float As[64 * 68];
    __shared__ float Bs[64 * 128];
    int t = threadIdx.x;
    int p0 = blockIdx.x * 64;
    for (int g = t; g < 64 * 16; g += 256) {
        int c = g >> 4, o4 = (g & 15) * 4;
        float4 wa = *(const float4*)&w1[c * 64 + o4];
        float4 wb = *(const float4*)&w1[(64 + c) * 64 + o4];
        float4 d; d.x = wa.x - wb.x; d.y = wa.y - wb.y; d.z = wa.z - wb.z; d.w = wa.w - wb.w;
        *(float4*)&Bs[c * 128 + o4] = d;
    }
    for (int g = t; g < 64 * 16; g += 256) {
        int c = g >> 4, o4 = (g & 15) * 4;
        *(float4*)&Bs[c * 128 + 64 + o4] = *(const float4*)&w1[(64 + c) * 64 + o4];
    }
    {
        int pq = t >> 4, cq = t & 15;
        const float* xp = x + (size_t)(p0 + pq * 4) * 64 + cq * 4;
        float4 r0 = *(const float4*)&xp[0 * 64];
        float4 r1 = *(const float4*)&xp[1 * 64];
        float4 r2 = *(const float4*)&xp[2 * 64];
        float4 r3 = *(const float4*)&xp[3 * 64];
        float4 c0; c0.x = r0.x; c0.y = r1.x; c0.z = r2.x; c0.w = r3.x;
        float4 c1; c1.x = r0.y; c1.y = r1.y; c1.z = r2.y; c1.w = r3.y;
        float4 c2; c2.x = r0.z; c2.y = r1.z; c2.z = r2.z; c2.w = r3.z;
        float4 c3; c3.x = r0.w; c3.y = r1.w; c3.z = r2.w; c3.w = r3.w;
        *(float4*)&As[(cq * 4 + 0) * 68 + pq * 4] = c0;
        *(float4*)&As[(cq * 4 + 1) * 68 + pq * 4] = c1;
        *(float4*)&As[(cq * 4 + 2) * 68 + pq * 4] = c2;
        *(float4*)&As[(cq * 4 + 3) * 68 + pq * 4] = c3;
    }
    __syncthreads();
    int rg = t >> 4;
    int cg = t & 15;
    float acc[4][8];
    #pragma unroll
    for (int i = 0; i < 4; ++i)
        #pragma unroll
        for (int jj = 0; jj < 8; ++jj) acc[i][jj] = 0.f;
    #pragma unroll 4
    for (int c = 0; c < 64; ++c) {
        float4 a4 = *(const float4*)&As[c * 68 + rg * 4];
        float4 b0 = *(const float4*)&Bs[c * 128 + cg * 8];
        float4 b4 = *(const float4*)&Bs[c * 128 + cg * 8 + 4];
        float av[4] = {a4.x, a4.y, a4.z, a4.w};
        float bv[8] = {b0.x, b0.y, b0.z, b0.w, b4.x, b4.y, b4.z, b4.w};
        #pragma unroll
        for (int i = 0; i < 4; ++i)
            #pragma unroll
            for (int jj = 0; jj < 8; ++jj)
                acc[i][jj] = fmaf(av[i], bv[jj], acc[i][jj]);
    }
    if (cg < 8) {
        float4 bb0 = *(const float4*)&b1[cg * 8];
        float4 bb1 = *(const float4*)&b1[cg * 8 + 4];
        #pragma unroll
        for (int i = 0; i < 4; ++i) {
            size_t p = p0 + rg * 4 + i;
            float4 o0; o0.x = acc[i][0] + bb0.x; o0.y = acc[i][1] + bb0.y;
                       o0.z = acc[i][2] + bb0.z; o0.w = acc[i][3] + bb0.w;
            float4 o1; o1.x = acc[i][4] + bb1.x; o1.y = acc[i][5] + bb1.y;
                       o1.z = acc[i][6] + bb1.z; o1.w = acc[i][7] + bb1.w;
            *(float4*)&u[p * 64 + cg * 8]     = o0;
            *(float4*)&u[p * 64 + cg * 8 + 4] = o1;
        }
    } else {
        int o = (cg - 8) * 8;
        #pragma unroll
        for (int i = 0; i < 4; ++i) {
            size_t p = p0 + rg * 4 + i;
            float4 o0; o0.x = acc[i][0]; o0.y = acc[i][1]; o0.z = acc[i][2]; o0.w = acc[i][3];
            float4 o1; o1.x = acc[i][4]; o1.y = acc[i][5]; o1.z = acc[i][6]; o1.w = acc[i][7];
            *(float4*)&v[p * 64 + o]     = o0;
            *(float4*)&v[p * 64 + o + 4] = o1;
        }
    }
}

// ---------------- edge MFMA: wave = 1 point/step, A=relu(u+v) hi/lo, w2 hi/lo in VGPRs ----
// A-frag row m = neighbor index; B-frag n = out channel; C: row=(quad*4+reg)=k, col=m=o.
// Max over k = reg-max + shfl_xor(16,32). Epilogue emits fp32 + bf16 hi/lo (feeds knn).
__global__ __launch_bounds__(256) void edge_mfma_kernel(const float* __restrict__ u,
                                                        const float* __restrict__ v,
                                                        const int* __restrict__ idx,
                                                        const float* __restrict__ w2,
                                                        const float* __restrict__ b2,
                                                        float* __restrict__ out,
                                                        ushort_t* __restrict__ oh,
                                                        ushort_t* __restrict__ ol) {
    int wave = threadIdx.x >> 6, lane = threadIdx.x & 63;
    int m = lane & 15, quad = lane >> 4;
    // B frags: B[n=ct*16+m][k=kh*32+quad*8+e] = w2[k*64+n], split hi/lo (rne lo).
    bf16x8_t Bh[4][2], Bl[4][2];
    #pragma unroll
    for (int ct = 0; ct < 4; ++ct) {
        #pragma unroll
        for (int kh = 0; kh < 2; ++kh) {
            union { ushort_t s[8]; bf16x8_t v8; } H, L;
            #pragma unroll
            for (int e = 0; e < 8; ++e) {
                int k = kh * 32 + quad * 8 + e;
                float w = w2[k * 64 + ct * 16 + m];
                uint_t bits = __float_as_uint(w);
                H.s[e] = (ushort_t)(bits >> 16);
                float hif = __uint_as_float(bits & 0xFFFF0000u);
                L.s[e] = f2bf(w - hif);
            }
            Bh[ct][kh] = H.v8; Bl[ct][kh] = L.v8;
        }
    }
    int p0 = blockIdx.x * 16 + wave * 4;
    #pragma unroll
    for (int pi = 0; pi < 4; ++pi) {
        int p = p0 + pi;
        int b = p >> 10;
        int j = idx[p * 16 + m];                    // neighbor for A-row m
        const float* up = u + (size_t)p * 64;
        const float* vp = v + ((size_t)(b << 10) + j) * 64;
        bf16x8_t Ah[2], Al[2];
        #pragma unroll
        for (int kh = 0; kh < 2; ++kh) {
            int c0 = kh * 32 + quad * 8;
            float4 ua = *(const float4*)(up + c0);
            float4 ub = *(const float4*)(up + c0 + 4);
            float4 va = *(const float4*)(vp + c0);
            float4 vb = *(const float4*)(vp + c0 + 4);
            float f[8] = {ua.x + va.x, ua.y + va.y, ua.z + va.z, ua.w + va.w,
                          ub.x + vb.x, ub.y + vb.y, ub.z + vb.z, ub.w + vb.w};
            union { ushort_t s[8]; bf16x8_t v8; } H, L;
            #pragma unroll
            for (int e = 0; e < 8; ++e) {
                float g = fmaxf(f[e], 0.f);
                uint_t bits = __float_as_uint(g);
                H.s[e] = (ushort_t)(bits >> 16);
                float hif = __uint_as_float(bits & 0xFFFF0000u);
                L.s[e] = (ushort_t)(__float_as_uint(g - hif) >> 16); // trunc lo (g>=hif>=0)
            }
            Ah[kh] = H.v8; Al[kh] = L.v8;
        }
        float res[4];
        #pragma unroll
        for (int ct = 0; ct < 4; ++ct) {
            f32x4_t acc = {0.f, 0.f, 0.f, 0.f};
            acc = __builtin_amdgcn_mfma_f32_16x16x32_bf16(Ah[0], Bh[ct][0], acc, 0, 0, 0);
            acc = __builtin_amdgcn_mfma_f32_16x16x32_bf16(Ah[1], Bh[ct][1], acc, 0, 0, 0);
            acc = __builtin_amdgcn_mfma_f32_16x16x32_bf16(Ah[0], Bl[ct][0], acc, 0, 0, 0);
            acc = __builtin_amdgcn_mfma_f32_16x16x32_bf16(Ah[1], Bl[ct][1], acc, 0, 0, 0);
            acc = __builtin_amdgcn_mfma_f32_16x16x32_bf16(Al[0], Bh[ct][0], acc, 0, 0, 0);
            acc = __builtin_amdgcn_mfma_f32_16x16x32_bf16(Al[1], Bh[ct][1], acc, 0, 0, 0);
            float mm = fmaxf(fmaxf(acc[0], acc[1]), fmaxf(acc[2], acc[3]));
            mm = fmaxf(mm, __shfl_xor(mm, 16, 64));
            mm = fmaxf(mm, __shfl_xor(mm, 32, 64));
            res[ct] = mm;                           // col m's max over all 16 k
        }
        if (quad == 0) {
            #pragma unroll
            for (int ct = 0; ct < 4; ++ct) {
                int o = ct * 16 + m;
                float val = res[ct] + b2[o];
                out[(size_t)p * 64 + o] = val;
                uint_t bits = __float_as_uint(val);
                oh[(size_t)p * 64 + o] = (ushort_t)(bits >> 16);
                float hif = __uint_as_float(bits & 0xFFFF0000u);
                ol[(size_t)p * 64 + o] = f2bf(val - hif);
            }
        }
    }
}

// ---------------- final MLP 192->128->64->32->2 + log_softmax (block-tiled GEMM) ----
// block = 64 points; As=[192][64] fp32 (48K) + h-buf (16K) = 64 KB -> 2 blocks/CU.
// layer1 split into two N-halves interleaved with layer2 K-partials.
__global__ __launch_bounds__(256) void mlp_kernel(const float* __restrict__ x1,
                                                  const float* __restrict__ x2,
                                                  const float* __restrict__ x3,
                                                  const float* __restrict__ mw1, const float* __restrict__ mb1,
                                                  const float* __restrict__ mw2, const float* __restrict__ mb2,
                                                  const float* __restrict__ mw3, const float* __restrict__ mb3,
                                                  const float* __restrict__ mw4, const float* __restrict__ mb4,
                                                  float* __restrict__ out) {
    __shared__ float smem[192 * 64 + 64 * 64];     // 64 KB
    float* As  = smem;                              // [192][64]
    float* h1a = smem + 192 * 64;                   // [64][64] (one N-half of h1)
    float* h2  = smem;                              // [64][64] overlays As (dead)
    float* h3  = smem + 192 * 64;                   // [32][64] overlays h1a (dead)
    int t = threadIdx.x;
    int p0 = blockIdx.x * 64;
    // stage transposed concat [c][p]
    {
        int pq = t >> 4, cq = t & 15;
        const float* srcs[3] = {x1, x2, x3};
        #pragma unroll
        for (int s = 0; s < 3; ++s) {
            const float* xp = srcs[s] + (size_t)(p0 + pq * 4) * 64 + cq * 4;
            float4 r0 = *(const float4*)&xp[0 * 64];
            float4 r1 = *(const float4*)&xp[1 * 64];
            float4 r2 = *(const float4*)&xp[2 * 64];
            float4 r3 = *(const float4*)&xp[3 * 64];
            int cb = (s * 64 + cq * 4) * 64 + pq * 4;
            float4 c0; c0.x = r0.x; c0.y = r1.x; c0.z = r2.x; c0.w = r3.x;
            float4 c1; c1.x = r0.y; c1.y = r1.y; c1.z = r2.y; c1.w = r3.y;
            float4 c2; c2.x = r0.z; c2.y = r1.z; c2.z = r2.z; c2.w = r3.z;
            float4 c3; c3.x = r0.w; c3.y = r1.w; c3.z = r2.w; c3.w = r3.w;
            *(float4*)&As[cb]          = c0;
            *(float4*)&As[cb + 64]     = c1;
            *(float4*)&As[cb + 128]    = c2;
            *(float4*)&As[cb + 192]    = c3;
        }
    }
    __syncthreads();
    int rg = t >> 4, cg = t & 15;                   // 4 pts x 4 outs per thread
    float acc2[4][4];
    {
        float4 bb = *(const float4*)&mb2[cg * 4];
        #pragma unroll
        for (int i = 0; i < 4; ++i) {
            acc2[i][0] = bb.x; acc2[i][1] = bb.y; acc2[i][2] = bb.z; acc2[i][3] = bb.w;
        }
    }
    #pragma unroll
    for (int hN = 0; hN < 2; ++hN) {
        // L1 half: outs hN*64 + cg*4 .. +3
        float acc[4][4];
        {
            float4 bb = *(const float4*)&mb1[hN * 64 + cg * 4];
            #pragma unroll
            for (int i = 0; i < 4; ++i) {
                acc[i][0] = bb.x; acc[i][1] = bb.y; acc[i][2] = bb.z; acc[i][3] = bb.w;
            }
        }
        #pragma unroll 4
        for (int c = 0; c < 192; ++c) {
            float4 a4 = *(const float4*)&As[c * 64 + rg * 4];
            float4 b4 = *(const float4*)&mw1[c * 128 + hN * 64 + cg * 4];
            float av[4] = {a4.x, a4.y, a4.z, a4.w};
            float bv[4] = {b4.x, b4.y, b4.z, b4.w};
            #pragma unroll
            for (int i = 0; i < 4; ++i)
                #pragma unroll
                for (int jj = 0; jj < 4; ++jj)
                    acc[i][jj] = fmaf(av[i], bv[jj], acc[i][jj]);
        }
        #pragma unroll
        for (int jj = 0; jj < 4; ++jj) {
            float4 w;
            w.x = fmaxf(acc[0][jj], 0.f); w.y = fmaxf(acc[1][jj], 0.f);
            w.z = fmaxf(acc[2][jj], 0.f); w.w = fmaxf(acc[3][jj], 0.f);
            *(float4*)&h1a[(cg * 4 + jj) * 64 + rg * 4] = w;
        }
        __syncthreads();
        // L2 K-partial over this half's 64 h1 rows
        #pragma unroll 4
        for (int c = 0; c < 64; ++c) {
            float4 a4 = *(const float4*)&h1a[c * 64 + rg * 4];
            float4 b4 = *(const float4*)&mw2[(hN * 64 + c) * 64 + cg * 4];
            float av[4] = {a4.x, a4.y, a4.z, a4.w};
            float bv[4] = {b4.x, b4.y, b4.z, b4.w};
            #pragma unroll
            for (int i = 0; i < 4; ++i)
                #pragma unroll
                for (int jj = 0; jj < 4; ++jj)
                    acc2[i][jj] = fmaf(av[i], bv[jj], acc2[i][jj]);
        }
        __syncthreads();
    }
    // h2 write (overlays As; all As reads are >=2 syncs back)
    #pragma unroll
    for (int jj = 0; jj < 4; ++jj) {
        float4 w;
        w.x = fmaxf(acc2[0][jj], 0.f); w.y = fmaxf(acc2[1][jj], 0.f);
        w.z = fmaxf(acc2[2][jj], 0.f); w.w = fmaxf(acc2[3][jj], 0.f);
        *(float4*)&h2[(cg * 4 + jj) * 64 + rg * 4] = w;
    }
    __syncthreads();
    // L3: 64 -> 32, 4 pts x 2 outs
    float acc3[4][2];
    {
        float2 bb = *(const float2*)&mb3[cg * 2];
        #pragma unroll
        for (int i = 0; i < 4; ++i) { acc3[i][0] = bb.x; acc3[i][1] = bb.y; }
    }
    #pragma unroll 4
    for (int c = 0; c < 64; ++c) {
        float4 a4 = *(const float4*)&h2[c * 64 + rg * 4];
        float2 b2v = *(const float2*)&mw3[c * 32 + cg * 2];
        float av[4] = {a4.x, a4.y, a4.z, a4.w};
        #pragma unroll
        for (int i = 0; i < 4; ++i) {
            acc3[i][0] = fmaf(av[i], b2v.x, acc3[i][0]);
            acc3[i][1] = fmaf(av[i], b2v.y, acc3[i][1]);
        }
    }
    #pragma unroll
    for (int jj = 0; jj < 2; ++jj) {
        float4 w;
        w.x = fmaxf(acc3[0][jj], 0.f); w.y = fmaxf(acc3[1][jj], 0.f);
        w.z = fmaxf(acc3[2][jj], 0.f); w.w = fmaxf(acc3[3][jj], 0.f);
        *(float4*)&h3[(cg * 2 + jj) * 64 + rg * 4] = w;
    }
    __syncthreads();
    // L4 + log_softmax: thread t<64 -> point t
    if (t < 64) {
        float z0 = mb4[0], z1 = mb4[1];
        #pragma unroll 8
        for (int c = 0; c < 32; ++c) {
            float h = h3[c * 64 + t];
            z0 = fmaf(h, mw4[c * 2 + 0], z0);
            z1 = fmaf(h, mw4[c * 2 + 1], z1);
        }
        float mx = fmaxf(z0, z1);
        float ls = mx + logf(expf(z0 - mx) + expf(z1 - mx));
        float2 o; o.x = z0 - ls; o.y = z1 - ls;
        *(float2*)&out[(size_t)(p0 + t) * 2] = o;
    }
}

extern "C" void kernel_launch(void* const* d_in, const int* in_sizes, int n_in,
                              void* d_out, int out_size, void* d_ws, size_t ws_size,
                              hipStream_t stream) {
    const float* x0   = (const float*)d_in[0];
    const float* c1w1 = (const float*)d_in[1];  const float* c1b1 = (const float*)d_in[2];
    const float* c1w2 = (const float*)d_in[3];  const float* c1b2 = (const float*)d_in[4];
    const float* c2w1 = (const float*)d_in[5];  const float* c2b1 = (const float*)d_in[6];
    const float* c2w2 = (const float*)d_in[7];  const float* c2b2 = (const float*)d_in[8];
    const float* c3w1 = (const float*)d_in[9];  const float* c3b1 = (const float*)d_in[10];
    const float* c3w2 = (const float*)d_in[11]; const float* c3b2 = (const float*)d_in[12];
    const float* mw1  = (const float*)d_in[13]; const float* mb1  = (const float*)d_in[14];
    const float* mw2  = (const float*)d_in[15]; const float* mb2  = (const float*)d_in[16];
    const float* mw3  = (const float*)d_in[17]; const float* mb3  = (const float*)d_in[18];
    const float* mw4  = (const float*)d_in[19]; const float* mb4  = (const float*)d_in[20];

    float* ws = (float*)d_ws;
    const size_t NF = (size_t)NPOINTS * 64;
    float* x1 = ws;
    float* x2 = x1 + NF;
    float* x3 = x2 + NF;
    float* u  = x3 + NF;
    float* v  = u  + NF;
    float* sq = v  + NF;
    int*  idx = (int*)(sq + NPOINTS);
    ushort_t* xh = (ushort_t*)(idx + (size_t)NPOINTS * KNB);
    ushort_t* xl = xh + NF;
    uint_t* cand = (uint_t*)u;     // aliases u..v; dead ranges don't overlap in time
    float* out = (float*)d_out;

    // ---- layer 1 (C_in = 1): fp32 knn ----
    sqnorm_kernel<1><<<NPOINTS / 64, 64, 0, stream>>>(x0, sq);
    knn_part1_kernel<<<(NPOINTS / 64) * NCHUNK1, 64, 0, stream>>>(x0, sq, cand);
    knn_merge_kernel<NCHUNK1 * KNB><<<NPOINTS / 256, 256, 0, stream>>>(cand, idx);
    uv1_kernel<<<1024, 256, 0, stream>>>(x0, c1w1, c1b1, u, v);
    edge_mfma_kernel<<<NPOINTS / 16, 256, 0, stream>>>(u, v, idx, c1w2, c1b2, x1, xh, xl);
    // ---- layer 2: MFMA knn (xh/xl from edge L1) ----
    sqnorm_kernel<64><<<NPOINTS / 64, 64, 0, stream>>>(x1, sq);
    knn_mfma_kernel<<<NB * 16 * NCHUNK2, 64, 0, stream>>>(xh, xl, sq, cand);
    knn_merge_kernel<NCHUNK2 * 64><<<NPOINTS / 256, 256, 0, stream>>>(cand, idx);
    uv_gemm_kernel<<<NPOINTS / 64, 256, 0, stream>>>(x1, c2w1, c2b1, u, v);
    edge_mfma_kernel<<<NPOINTS / 16, 256, 0, stream>>>(u, v, idx, c2w2, c2b2, x2, xh, xl);
    // ---- layer 3: MFMA knn (xh/xl from edge L2) ----
    sqnorm_kernel<64><<<NPOINTS / 64, 64, 0, stream>>>(x2, sq);
    knn_mfma_kernel<<<NB * 16 * NCHUNK2, 64, 0, stream>>>(xh, xl, sq, cand);
    knn_merge_kernel<NCHUNK2 * 64><<<NPOINTS / 256, 256, 0, stream>>>(cand, idx);
    uv_gemm_kernel<<<NPOINTS / 64, 256, 0, stream>>>(x2, c3w1, c3b1, u, v);
    edge_mfma_kernel<<<NPOINTS / 16, 256, 0, stream>>>(u, v, idx, c3w2, c3b2, x3, xh, xl);
    // ---- final MLP + log_softmax ----
    mlp_kernel<<<1024, 256, 0, stream>>>(x1, x2, x3, mw1, mb1, mw2, mb2,
                                         mw3, mb3, mw4, mb4, out);
}

// Round 7
// 791.355 us; speedup vs baseline: 5.3553x; 1.0168x over previous
//
#include <hip/hip_runtime.h>
#include <math.h>

typedef unsigned short ushort_t;
typedef unsigned int uint_t;
typedef __bf16 bf16x8_t __attribute__((ext_vector_type(8)));
typedef float f32x4_t __attribute__((ext_vector_type(4)));

static constexpr int NPTS = 1024;
static constexpr int NB = 64;
static constexpr int NPOINTS = NB * NPTS;   // 65536
static constexpr int KNB = 16;
static constexpr int NCHUNK1 = 4;           // layer-1 fp32 knn chunking
static constexpr int NCHUNK2 = 2;           // mfma knn chunking

__device__ __forceinline__ ushort_t f2bf(float f) {
    uint_t u = __float_as_uint(f);
    uint_t r = (u + 0x7FFFu + ((u >> 16) & 1u)) >> 16;
    return (ushort_t)r;
}
__device__ __forceinline__ float bf2f(ushort_t h) {
    return __uint_as_float(((uint_t)h) << 16);
}
// pack distance (clamped >=0, 22 bits kept) + batch-local j (10 bits).
__device__ __forceinline__ uint_t packdj(float d, int j) {
    return (__float_as_uint(fmaxf(d, 0.f)) & 0xFFFFFC00u) | (uint_t)j;
}
// branch-free sorted-16 insert (min/max network, exec-uniform).
__device__ __forceinline__ void insert16(uint_t* L, uint_t c) {
    L[15] = (c < L[15]) ? c : L[15];
    #pragma unroll
    for (int k = 15; k > 0; --k) {
        uint_t a = L[k - 1], b = L[k];
        L[k - 1] = a < b ? a : b;
        L[k]     = a < b ? b : a;
    }
}

// ---------------- squared norms ----------------
template<int C>
__global__ __launch_bounds__(64) void sqnorm_kernel(const float* __restrict__ x,
                                                    float* __restrict__ sq) {
    int p = blockIdx.x * 64 + threadIdx.x;
    const float* xp = x + (size_t)p * C;
    float s;
    if constexpr (C == 1) {
        s = xp[0] * xp[0];
    } else {
        float a0 = 0.f, a1 = 0.f, a2 = 0.f, a3 = 0.f;
        #pragma unroll
        for (int d = 0; d < C; d += 4) {
            a0 = fmaf(xp[d + 0], xp[d + 0], a0);
            a1 = fmaf(xp[d + 1], xp[d + 1], a1);
            a2 = fmaf(xp[d + 2], xp[d + 2], a2);
            a3 = fmaf(xp[d + 3], xp[d + 3], a3);
        }
        s = (a0 + a1) + (a2 + a3);
    }
    sq[p] = s;
}

// ---------------- w1^T -> bf16 hi/lo prep: w1t[n][k], n<128, k<192 ----------------
__global__ __launch_bounds__(192) void w1prep_kernel(const float* __restrict__ mw1,
                                                     ushort_t* __restrict__ w1th,
                                                     ushort_t* __restrict__ w1tl) {
    int n = blockIdx.x, k = threadIdx.x;
    float w = mw1[k * 128 + n];
    uint_t bits = __float_as_uint(w);
    ushort_t hi = (ushort_t)(bits >> 16);
    float hif = __uint_as_float(bits & 0xFFFF0000u);
    w1th[n * 192 + k] = hi;
    w1tl[n * 192 + k] = f2bf(w - hif);
}

// ---------------- layer-1 knn (C=1): fp32 LDS-tile scan, packed top-16 ----------------
__global__ __launch_bounds__(64) void knn_part1_kernel(const float* __restrict__ pts,
                                                       const float* __restrict__ sq,
                                                       uint_t* __restrict__ cand) {
    constexpr int JT = 32;
    constexpr int JC = NPTS / NCHUNK1;           // 256
    __shared__ float tile[JT];
    __shared__ float tsq[JT];
    int chunk = blockIdx.x & (NCHUNK1 - 1);
    int pblk  = blockIdx.x >> 2;
    int i  = pblk * 64 + threadIdx.x;
    int b  = i >> 10;
    int il = i & 1023;
    const float* base = pts + (size_t)(b << 10);
    float xi = base[il];
    float sqi = sq[i];
    const float* sqb = sq + (b << 10);

    uint_t lst[KNB];
    #pragma unroll
    for (int k = 0; k < KNB; ++k) lst[k] = 0xFFFFFFFFu;

    int j0 = chunk * JC;
    for (int jt = 0; jt < JC; jt += JT) {
        if (threadIdx.x < JT) {
            tile[threadIdx.x] = base[j0 + jt + threadIdx.x];
            tsq[threadIdx.x] = sqb[j0 + jt + threadIdx.x];
        }
        __syncthreads();
        #pragma unroll 4
        for (int jj = 0; jj < JT; ++jj) {
            float dist = sqi + tsq[jj] - 2.0f * (xi * tile[jj]);
            insert16(lst, packdj(dist, j0 + jt + jj));
        }
        __syncthreads();
    }
    #pragma unroll
    for (int k = 0; k < KNB; ++k)
        cand[(size_t)(chunk * KNB + k) * NPOINTS + i] = lst[k];
}

// ---------------- MFMA knn (C=64): 16x16x32 bf16 hi/lo, packed 4-sublist top-16 ----
__global__ __launch_bounds__(64, 2) void knn_mfma_kernel(const ushort_t* __restrict__ xh,
                                                         const ushort_t* __restrict__ xl,
                                                         const float* __restrict__ sq,
                                                         uint_t* __restrict__ cand) {
    constexpr int JC = NPTS / NCHUNK2;           // 512
    __shared__ uint_t dbuf[16 * 68];
    __shared__ float sqs[JC];
    int chunk = blockIdx.x & (NCHUNK2 - 1);
    int ib    = (blockIdx.x >> 1) & 15;
    int b     = blockIdx.x >> 5;
    int i0    = b * NPTS + ib * 64;
    int lane  = threadIdx.x;
    int m = lane & 15, quad = lane >> 4;
    int j0c = chunk * JC;

    for (int t = lane; t < JC; t += 64) sqs[t] = sq[b * NPTS + j0c + t];

    bf16x8_t Ah[4][2], Al[4][2];
    #pragma unroll
    for (int it = 0; it < 4; ++it) {
        #pragma unroll
        for (int kh = 0; kh < 2; ++kh) {
            size_t off = ((size_t)(i0 + it * 16 + m)) * 64 + kh * 32 + quad * 8;
            Ah[it][kh] = *(const bf16x8_t*)(xh + off);
            Al[it][kh] = *(const bf16x8_t*)(xl + off);
        }
    }
    float4 sqi[4];
    #pragma unroll
    for (int it = 0; it < 4; ++it)
        sqi[it] = *(const float4*)&sq[i0 + it * 16 + quad * 4];

    uint_t lst[4][KNB];
    #pragma unroll
    for (int s = 0; s < 4; ++s)
        #pragma unroll
        for (int k = 0; k < KNB; ++k) lst[s][k] = 0xFFFFFFFFu;
    __syncthreads();

    for (int g = 0; g < JC / 16; ++g) {
        int jg = j0c + g * 16;                       // batch-local j base
        size_t boff = ((size_t)(b * NPTS + jg + m)) * 64 + quad * 8;
        bf16x8_t Bh0 = *(const bf16x8_t*)(xh + boff);
        bf16x8_t Bh1 = *(const bf16x8_t*)(xh + boff + 32);
        bf16x8_t Bl0 = *(const bf16x8_t*)(xl + boff);
        bf16x8_t Bl1 = *(const bf16x8_t*)(xl + boff + 32);
        float sqj = sqs[g * 16 + m];
        int jm = jg + m;
        #pragma unroll
        for (int it = 0; it < 4; ++it) {
            f32x4_t acc = {0.f, 0.f, 0.f, 0.f};
            acc = __builtin_amdgcn_mfma_f32_16x16x32_bf16(Ah[it][0], Bh0, acc, 0, 0, 0);
            acc = __builtin_amdgcn_mfma_f32_16x16x32_bf16(Ah[it][1], Bh1, acc, 0, 0, 0);
            acc = __builtin_amdgcn_mfma_f32_16x16x32_bf16(Ah[it][0], Bl0, acc, 0, 0, 0);
            acc = __builtin_amdgcn_mfma_f32_16x16x32_bf16(Ah[it][1], Bl1, acc, 0, 0, 0);
            acc = __builtin_amdgcn_mfma_f32_16x16x32_bf16(Al[it][0], Bh0, acc, 0, 0, 0);
            acc = __builtin_amdgcn_mfma_f32_16x16x32_bf16(Al[it][1], Bh1, acc, 0, 0, 0);
            uint4 pv;
            pv.x = packdj(sqi[it].x + sqj - 2.0f * acc[0], jm);
            pv.y = packdj(sqi[it].y + sqj - 2.0f * acc[1], jm);
            pv.z = packdj(sqi[it].z + sqj - 2.0f * acc[2], jm);
            pv.w = packdj(sqi[it].w + sqj - 2.0f * acc[3], jm);
            *(uint4*)&dbuf[m * 68 + it * 16 + quad * 4] = pv;
        }
        __syncthreads();
        #pragma unroll
        for (int jj = 0; jj < 16; ++jj)
            insert16(lst[jj & 3], dbuf[jj * 68 + lane]);
        __syncthreads();
    }
    #pragma unroll
    for (int s = 0; s < 4; ++s)
        #pragma unroll
        for (int k = 0; k < KNB; ++k)
            cand[(size_t)(chunk * 64 + s * 16 + k) * NPOINTS + i0 + lane] = lst[s][k];
}

// ---------------- knn merge: NC packed candidates -> final top-16 indices ----------------
template<int NC>
__global__ __launch_bounds__(256) void knn_merge_kernel(const uint_t* __restrict__ cand,
                                                        int* __restrict__ idx_out) {
    int i = blockIdx.x * 256 + threadIdx.x;
    uint_t lst[KNB];
    #pragma unroll
    for (int k = 0; k < KNB; ++k) lst[k] = 0xFFFFFFFFu;
    #pragma unroll 4
    for (int t = 0; t < NC; ++t)
        insert16(lst, cand[(size_t)t * NPOINTS + i]);
    int* op = idx_out + (size_t)i * KNB;
    #pragma unroll
    for (int k = 0; k < KNB; ++k) op[k] = (int)(lst[k] & 0x3FFu);
}

// ---------------- uv for layer 1 (C_in = 1): elementwise ----------------
__global__ __launch_bounds__(256) void uv1_kernel(const float* __restrict__ x,
                                                  const float* __restrict__ w1,
                                                  const float* __restrict__ b1,
                                                  float* __restrict__ u,
                                                  float* __restrict__ v) {
    int lane = threadIdx.x & 63, wave = threadIdx.x >> 6;
    float wa = w1[lane], wb = w1[64 + lane], bb = b1[lane];
    float wd = wa - wb;
    int gw = blockIdx.x * 4 + wave;
    for (int p = gw; p < NPOINTS; p += 4096) {
        float xv = x[p];
        u[(size_t)p * 64 + lane] = fmaf(xv, wd, bb);
        v[(size_t)p * 64 + lane] = xv * wb;
    }
}

// ---------------- uv GEMM (CIN=64) ----------------
__global__ __launch_bounds__(256) void uv_gemm_kernel(const float* __restrict__ x,
                                                      const float* __restrict__ w1,
                                                      const float* __restrict__ b1,
                                                      float* __restrict__ u,
                                                      float* __restrict__ v) {
    __shared__ float As[64 * 68];
    __shared__ float Bs[64 * 128];
    int t = threadIdx.x;
    int p0 = blockIdx.x * 64;
    for (int g = t; g < 64 * 16; g += 256) {
        int c = g >> 4, o4 = (g & 15) * 4;
        float4 wa = *(const float4*)&w1[c * 64 + o4];
        float4 wb = *(const float4*)&w1[(64 + c) * 64 + o4];
        float4 d; d.x = wa.x - wb.x; d.y = wa.y - wb.y; d.z = wa.z - wb.z; d.w = wa.w - wb.w;
        *(float4*)&Bs[c * 128 + o4] = d;
    }
    for (int g = t; g < 64 * 16; g += 256) {
        int c = g >> 4, o4 = (g & 15) * 4;
        *(float4*)&Bs[c * 128 + 64 + o4] = *(const float4*)&w1[(64 + c) * 64 + o4];
    }
    {
        int pq = t >> 4, cq = t & 15;
        const float* xp = x + (size_t)(p0 + pq * 4) * 64 + cq * 4;
        float4 r0 = *(const float4*)&xp[0 * 64];
        float4 r1 = *(const float4*)&xp[1 * 64];
        float4 r2 = *(const float4*)&xp[2 * 64];
        float4 r3 = *(const float4*)&xp[3 * 64];
        float4 c0; c0.x = r0.x; c0.y = r1.x; c0.z = r2.x; c0.w = r3.x;
        float4 c1; c1.x = r0.y; c1.y = r1.y; c1.z = r2.y; c1.w = r3.y;
        float4 c2; c2.x = r0.z; c2.y = r1.z; c2.z = r2.z; c2.w = r3.z;
        float4 c3; c3.x = r0.w; c3.y = r1.w; c3.z = r2.w; c3.w = r3.w;
        *(float4*)&As[(cq * 4 + 0) * 68 + pq * 4] = c0;
        *(float4*)&As[(cq * 4 + 1) * 68 + pq * 4] = c1;
        *(float4*)&As[(cq * 4 + 2) * 68 + pq * 4] = c2;
        *(float4*)&As[(cq * 4 + 3) * 68 + pq * 4] = c3;
    }
    __syncthreads();
    int rg = t >> 4;
    int cg = t & 15;
    float acc[4][8];
    #pragma unroll
    for (int i = 0; i < 4; ++i)
        #pragma unroll
        for (int jj = 0; jj < 8; ++jj) acc[i][jj] = 0.f;
    #pragma unroll 4
    for (int c = 0; c < 64; ++c) {
        float4 a4 = *(const float4*)&As[c * 68 + rg * 4];
        float4 b0 = *(const float4*)&Bs[c * 128 + cg * 8];
        float4 b4 = *(const float4*)&Bs[c * 128 + cg * 8 + 4];
        float av[4] = {a4.x, a4.y, a4.z, a4.w};
        float bv[8] = {b0.x, b0.y, b0.z, b0.w, b4.x, b4.y, b4.z, b4.w};
        #pragma unroll
        for (int i = 0; i < 4; ++i)
            #pragma unroll
            for (int jj = 0; jj < 8; ++jj)
                acc[i][jj] = fmaf(av[i], bv[jj], acc[i][jj]);
    }
    if (cg < 8) {
        float4 bb0 = *(const float4*)&b1[cg * 8];
        float4 bb1 = *(const float4*)&b1[cg * 8 + 4];
        #pragma unroll
        for (int i = 0; i < 4; ++i) {
            size_t p = p0 + rg * 4 + i;
            float4 o0; o0.x = acc[i][0] + bb0.x; o0.y = acc[i][1] + bb0.y;
                       o0.z = acc[i][2] + bb0.z; o0.w = acc[i][3] + bb0.w;
            float4 o1; o1.x = acc[i][4] + bb1.x; o1.y = acc[i][5] + bb1.y;
                       o1.z = acc[i][6] + bb1.z; o1.w = acc[i][7] + bb1.w;
            *(float4*)&u[p * 64 + cg * 8]     = o0;
            *(float4*)&u[p * 64 + cg * 8 + 4] = o1;
        }
    } else {
        int o = (cg - 8) * 8;
        #pragma unroll
        for (int i = 0; i < 4; ++i) {
            size_t p = p0 + rg * 4 + i;
            float4 o0; o0.x = acc[i][0]; o0.y = acc[i][1]; o0.z = acc[i][2]; o0.w = acc[i][3];
            float4 o1; o1.x = acc[i][4]; o1.y = acc[i][5]; o1.z = acc[i][6]; o1.w = acc[i][7];
            *(float4*)&v[p * 64 + o]     = o0;
            *(float4*)&v[p * 64 + o + 4] = o1;
        }
    }
}

// ---------------- edge MFMA: wave = 1 point/step, A=relu(u+v) hi/lo, w2 hi/lo in VGPRs ----
// WF32: also write fp32 output (needed when a later stage reads fp32).
template<bool WF32>
__global__ __launch_bounds__(256) void edge_mfma_kernel(const float* __restrict__ u,
                                                        const float* __restrict__ v,
                                                        const int* __restrict__ idx,
                                                        const float* __restrict__ w2,
                                                        const float* __restrict__ b2,
                                                        float* __restrict__ out,
                                                        ushort_t* __restrict__ oh,
                                                        ushort_t* __restrict__ ol) {
    int wave = threadIdx.x >> 6, lane = threadIdx.x & 63;
    int m = lane & 15, quad = lane >> 4;
    bf16x8_t Bh[4][2], Bl[4][2];
    #pragma unroll
    for (int ct = 0; ct < 4; ++ct) {
        #pragma unroll
        for (int kh = 0; kh < 2; ++kh) {
            union { ushort_t s[8]; bf16x8_t v8; } H, L;
            #pragma unroll
            for (int e = 0; e < 8; ++e) {
                int k = kh * 32 + quad * 8 + e;
                float w = w2[k * 64 + ct * 16 + m];
                uint_t bits = __float_as_uint(w);
                H.s[e] = (ushort_t)(bits >> 16);
                float hif = __uint_as_float(bits & 0xFFFF0000u);
                L.s[e] = f2bf(w - hif);
            }
            Bh[ct][kh] = H.v8; Bl[ct][kh] = L.v8;
        }
    }
    int p0 = blockIdx.x * 16 + wave * 4;
    #pragma unroll
    for (int pi = 0; pi < 4; ++pi) {
        int p = p0 + pi;
        int b = p >> 10;
        int j = idx[p * 16 + m];                    // neighbor for A-row m
        const float* up = u + (size_t)p * 64;
        const float* vp = v + ((size_t)(b << 10) + j) * 64;
        bf16x8_t Ah[2], Al[2];
        #pragma unroll
        for (int kh = 0; kh < 2; ++kh) {
            int c0 = kh * 32 + quad * 8;
            float4 ua = *(const float4*)(up + c0);
            float4 ub = *(const float4*)(up + c0 + 4);
            float4 va = *(const float4*)(vp + c0);
            float4 vb = *(const float4*)(vp + c0 + 4);
            float f[8] = {ua.x + va.x, ua.y + va.y, ua.z + va.z, ua.w + va.w,
                          ub.x + vb.x, ub.y + vb.y, ub.z + vb.z, ub.w + vb.w};
            union { ushort_t s[8]; bf16x8_t v8; } H, L;
            #pragma unroll
            for (int e = 0; e < 8; ++e) {
                float g = fmaxf(f[e], 0.f);
                uint_t bits = __float_as_uint(g);
                H.s[e] = (ushort_t)(bits >> 16);
                float hif = __uint_as_float(bits & 0xFFFF0000u);
                L.s[e] = (ushort_t)(__float_as_uint(g - hif) >> 16);
            }
            Ah[kh] = H.v8; Al[kh] = L.v8;
        }
        float res[4];
        #pragma unroll
        for (int ct = 0; ct < 4; ++ct) {
            f32x4_t acc = {0.f, 0.f, 0.f, 0.f};
            acc = __builtin_amdgcn_mfma_f32_16x16x32_bf16(Ah[0], Bh[ct][0], acc, 0, 0, 0);
            acc = __builtin_amdgcn_mfma_f32_16x16x32_bf16(Ah[1], Bh[ct][1], acc, 0, 0, 0);
            acc = __builtin_amdgcn_mfma_f32_16x16x32_bf16(Ah[0], Bl[ct][0], acc, 0, 0, 0);
            acc = __builtin_amdgcn_mfma_f32_16x16x32_bf16(Ah[1], Bl[ct][1], acc, 0, 0, 0);
            acc = __builtin_amdgcn_mfma_f32_16x16x32_bf16(Al[0], Bh[ct][0], acc, 0, 0, 0);
            acc = __builtin_amdgcn_mfma_f32_16x16x32_bf16(Al[1], Bh[ct][1], acc, 0, 0, 0);
            float mm = fmaxf(fmaxf(acc[0], acc[1]), fmaxf(acc[2], acc[3]));
            mm = fmaxf(mm, __shfl_xor(mm, 16, 64));
            mm = fmaxf(mm, __shfl_xor(mm, 32, 64));
            res[ct] = mm;
        }
        if (quad == 0) {
            #pragma unroll
            for (int ct = 0; ct < 4; ++ct) {
                int o = ct * 16 + m;
                float val = res[ct] + b2[o];
                if constexpr (WF32) out[(size_t)p * 64 + o] = val;
                uint_t bits = __float_as_uint(val);
                oh[(size_t)p * 64 + o] = (ushort_t)(bits >> 16);
                float hif = __uint_as_float(bits & 0xFFFF0000u);
                ol[(size_t)p * 64 + o] = f2bf(val - hif);
            }
        }
    }
}

// ---------------- final MLP: L1 (192->128) via MFMA hi/lo, L2-L4 fp32 from LDS ----
// block = 256 (4 waves), 64 points; wave w = points w*16..w*16+15 (m-tile).
// h1/h2/h3 LDS [channel][point] stride 68 (bank-spread); 52 KB -> 3 blocks/CU.
__global__ __launch_bounds__(256) void mlp_kernel(const ushort_t* __restrict__ xh1,
                                                  const ushort_t* __restrict__ xl1,
                                                  const ushort_t* __restrict__ xh2,
                                                  const ushort_t* __restrict__ xl2,
                                                  const ushort_t* __restrict__ xh3,
                                                  const ushort_t* __restrict__ xl3,
                                                  const ushort_t* __restrict__ w1th,
                                                  const ushort_t* __restrict__ w1tl,
                                                  const float* __restrict__ mb1,
                                                  const float* __restrict__ mw2, const float* __restrict__ mb2,
                                                  const float* __restrict__ mw3, const float* __restrict__ mb3,
                                                  const float* __restrict__ mw4, const float* __restrict__ mb4,
                                                  float* __restrict__ out) {
    __shared__ float smem[128 * 68 + 64 * 68];
    float* h1 = smem;               // [128][68]
    float* h2 = smem + 128 * 68;    // [64][68]
    float* h3 = smem;               // [32][68] overlays h1 (dead after L2)
    int t = threadIdx.x;
    int wave = t >> 6, lane = t & 63;
    int m = lane & 15, quad = lane >> 4;
    int p0 = blockIdx.x * 64;
    int pw = p0 + wave * 16;                        // this wave's 16 points

    // ---- L1 MFMA: 6 k-steps x 8 n-tiles x 3 hi/lo terms ----
    f32x4_t acc1[8];
    #pragma unroll
    for (int nt = 0; nt < 8; ++nt) acc1[nt] = (f32x4_t){0.f, 0.f, 0.f, 0.f};
    const ushort_t* HS[3] = {xh1, xh2, xh3};
    const ushort_t* LS[3] = {xl1, xl2, xl3};
    #pragma unroll
    for (int ks = 0; ks < 6; ++ks) {
        size_t aoff = (size_t)(pw + m) * 64 + (ks & 1) * 32 + quad * 8;
        bf16x8_t Ah = *(const bf16x8_t*)(HS[ks >> 1] + aoff);
        bf16x8_t Al = *(const bf16x8_t*)(LS[ks >> 1] + aoff);
        #pragma unroll
        for (int nt = 0; nt < 8; ++nt) {
            size_t boff = (size_t)(nt * 16 + m) * 192 + ks * 32 + quad * 8;
            bf16x8_t Bh = *(const bf16x8_t*)(w1th + boff);
            bf16x8_t Bl = *(const bf16x8_t*)(w1tl + boff);
            acc1[nt] = __builtin_amdgcn_mfma_f32_16x16x32_bf16(Ah, Bh, acc1[nt], 0, 0, 0);
            acc1[nt] = __builtin_amdgcn_mfma_f32_16x16x32_bf16(Ah, Bl, acc1[nt], 0, 0, 0);
            acc1[nt] = __builtin_amdgcn_mfma_f32_16x16x32_bf16(Al, Bh, acc1[nt], 0, 0, 0);
        }
    }
    // C: row = quad*4+reg (point-in-tile), col = m (n-in-tile). relu+bias -> h1[n][p]
    #pragma unroll
    for (int nt = 0; nt < 8; ++nt) {
        float bb = mb1[nt * 16 + m];
        float4 w;
        w.x = fmaxf(acc1[nt][0] + bb, 0.f);
        w.y = fmaxf(acc1[nt][1] + bb, 0.f);
        w.z = fmaxf(acc1[nt][2] + bb, 0.f);
        w.w = fmaxf(acc1[nt][3] + bb, 0.f);
        *(float4*)&h1[(nt * 16 + m) * 68 + wave * 16 + quad * 4] = w;
    }
    __syncthreads();

    // ---- L2: 128 -> 64 fp32; thread = 4 pts (rg) x 4 outs (cg) ----
    int rg = t >> 4, cg = t & 15;
    float acc2[4][4];
    {
        float4 bb = *(const float4*)&mb2[cg * 4];
        #pragma unroll
        for (int i = 0; i < 4; ++i) {
            acc2[i][0] = bb.x; acc2[i][1] = bb.y; acc2[i][2] = bb.z; acc2[i][3] = bb.w;
        }
    }
    #pragma unroll 4
    for (int c = 0; c < 128; ++c) {
        float4 a4 = *(const float4*)&h1[c * 68 + rg * 4];
        float4 b4 = *(const float4*)&mw2[c * 64 + cg * 4];
        float av[4] = {a4.x, a4.y, a4.z, a4.w};
        float bv[4] = {b4.x, b4.y, b4.z, b4.w};
        #pragma unroll
        for (int i = 0; i < 4; ++i)
            #pragma unroll
            for (int jj = 0; jj < 4; ++jj)
                acc2[i][jj] = fmaf(av[i], bv[jj], acc2[i][jj]);
    }
    #pragma unroll
    for (int jj = 0; jj < 4; ++jj) {
        float4 w;
        w.x = fmaxf(acc2[0][jj], 0.f); w.y = fmaxf(acc2[1][jj], 0.f);
        w.z = fmaxf(acc2[2][jj], 0.f); w.w = fmaxf(acc2[3][jj], 0.f);
        *(float4*)&h2[(cg * 4 + jj) * 68 + rg * 4] = w;
    }
    __syncthreads();
    // ---- L3: 64 -> 32 (h3 overlays h1 -- all h1 reads complete before this barrier) ----
    float acc3[4][2];
    {
        float2 bb = *(const float2*)&mb3[cg * 2];
        #pragma unroll
        for (int i = 0; i < 4; ++i) { acc3[i][0] = bb.x; acc3[i][1] = bb.y; }
    }
    #pragma unroll 4
    for (int c = 0; c < 64; ++c) {
        float4 a4 = *(const float4*)&h2[c * 68 + rg * 4];
        float2 b2v = *(const float2*)&mw3[c * 32 + cg * 2];
        float av[4] = {a4.x, a4.y, a4.z, a4.w};
        #pragma unroll
        for (int i = 0; i < 4; ++i) {
            acc3[i][0] = fmaf(av[i], b2v.x, acc3[i][0]);
            acc3[i][1] = fmaf(av[i], b2v.y, acc3[i][1]);
        }
    }
    #pragma unroll
    for (int jj = 0; jj < 2; ++jj) {
        float4 w;
        w.x = fmaxf(acc3[0][jj], 0.f); w.y = fmaxf(acc3[1][jj], 0.f);
        w.z = fmaxf(acc3[2][jj], 0.f); w.w = fmaxf(acc3[3][jj], 0.f);
        *(float4*)&h3[(cg * 2 + jj) * 68 + rg * 4] = w;
    }
    __syncthreads();
    // ---- L4 + log_softmax: thread t<64 -> point t ----
    if (t < 64) {
        float z0 = mb4[0], z1 = mb4[1];
        #pragma unroll 8
        for (int c = 0; c < 32; ++c) {
            float h = h3[c * 68 + t];
            z0 = fmaf(h, mw4[c * 2 + 0], z0);
            z1 = fmaf(h, mw4[c * 2 + 1], z1);
        }
        float mx = fmaxf(z0, z1);
        float ls = mx + logf(expf(z0 - mx) + expf(z1 - mx));
        float2 o; o.x = z0 - ls; o.y = z1 - ls;
        *(float2*)&out[(size_t)(p0 + t) * 2] = o;
    }
}

extern "C" void kernel_launch(void* const* d_in, const int* in_sizes, int n_in,
                              void* d_out, int out_size, void* d_ws, size_t ws_size,
                              hipStream_t stream) {
    const float* x0   = (const float*)d_in[0];
    const float* c1w1 = (const float*)d_in[1];  const float* c1b1 = (const float*)d_in[2];
    const float* c1w2 = (const float*)d_in[3];  const float* c1b2 = (const float*)d_in[4];
    const float* c2w1 = (const float*)d_in[5];  const float* c2b1 = (const float*)d_in[6];
    const float* c2w2 = (const float*)d_in[7];  const float* c2b2 = (const float*)d_in[8];
    const float* c3w1 = (const float*)d_in[9];  const float* c3b1 = (const float*)d_in[10];
    const float* c3w2 = (const float*)d_in[11]; const float* c3b2 = (const float*)d_in[12];
    const float* mw1  = (const float*)d_in[13]; const float* mb1  = (const float*)d_in[14];
    const float* mw2  = (const float*)d_in[15]; const float* mb2  = (const float*)d_in[16];
    const float* mw3  = (const float*)d_in[17]; const float* mb3  = (const float*)d_in[18];
    const float* mw4  = (const float*)d_in[19]; const float* mb4  = (const float*)d_in[20];

    float* ws = (float*)d_ws;
    const size_t NF = (size_t)NPOINTS * 64;
    float* x1 = ws;                      // fp32 (uv L2 + sqnorm L2 input)
    float* x2 = x1 + NF;                 // fp32 (uv L3 + sqnorm L3 input)
    ushort_t* xh3 = (ushort_t*)(x2 + NF);   // layer-3 hi/lo reuse old x3 slot
    ushort_t* xl3 = xh3 + NF;
    float* u  = (float*)(xl3 + NF);
    float* v  = u + NF;
    float* sq = v + NF;
    int*  idx = (int*)(sq + NPOINTS);
    ushort_t* xh1 = (ushort_t*)(idx + (size_t)NPOINTS * KNB);
    ushort_t* xl1 = xh1 + NF;
    ushort_t* xh2 = xl1 + NF;
    ushort_t* xl2 = xh2 + NF;
    ushort_t* w1th = xl2 + NF;
    ushort_t* w1tl = w1th + 128 * 192;
    uint_t* cand = (uint_t*)u;     // aliases u..v; dead ranges don't overlap in time
    float* out = (float*)d_out;

    // ---- weight prep (w1^T bf16 hi/lo) ----
    w1prep_kernel<<<128, 192, 0, stream>>>(mw1, w1th, w1tl);
    // ---- layer 1 (C_in = 1): fp32 knn ----
    sqnorm_kernel<1><<<NPOINTS / 64, 64, 0, stream>>>(x0, sq);
    knn_part1_kernel<<<(NPOINTS / 64) * NCHUNK1, 64, 0, stream>>>(x0, sq, cand);
    knn_merge_kernel<NCHUNK1 * KNB><<<NPOINTS / 256, 256, 0, stream>>>(cand, idx);
    uv1_kernel<<<1024, 256, 0, stream>>>(x0, c1w1, c1b1, u, v);
    edge_mfma_kernel<true><<<NPOINTS / 16, 256, 0, stream>>>(u, v, idx, c1w2, c1b2, x1, xh1, xl1);
    // ---- layer 2: MFMA knn on xh1/xl1 ----
    sqnorm_kernel<64><<<NPOINTS / 64, 64, 0, stream>>>(x1, sq);
    knn_mfma_kernel<<<NB * 16 * NCHUNK2, 64, 0, stream>>>(xh1, xl1, sq, cand);
    knn_merge_kernel<NCHUNK2 * 64><<<NPOINTS / 256, 256, 0, stream>>>(cand, idx);
    uv_gemm_kernel<<<NPOINTS / 64, 256, 0, stream>>>(x1, c2w1, c2b1, u, v);
    edge_mfma_kernel<true><<<NPOINTS / 16, 256, 0, stream>>>(u, v, idx, c2w2, c2b2, x2, xh2, xl2);
    // ---- layer 3: MFMA knn on xh2/xl2 ----
    sqnorm_kernel<64><<<NPOINTS / 64, 64, 0, stream>>>(x2, sq);
    knn_mfma_kernel<<<NB * 16 * NCHUNK2, 64, 0, stream>>>(xh2, xl2, sq, cand);
    knn_merge_kernel<NCHUNK2 * 64><<<NPOINTS / 256, 256, 0, stream>>>(cand, idx);
    uv_gemm_kernel<<<NPOINTS / 64, 256, 0, stream>>>(x2, c3w1, c3b1, u, v);
    edge_mfma_kernel<false><<<NPOINTS / 16, 256, 0, stream>>>(u, v, idx, c3w2, c3b2, nullptr, xh3, xl3);
    // ---- final MLP + log_softmax ----
    mlp_kernel<<<1024, 256, 0, stream>>>(xh1, xl1, xh2, xl2, xh3, xl3, w1th, w1tl,
                                         mb1, mw2, mb2, mw3, mb3, mw4, mb4, out);
}